// Round 7
// baseline (375.990 us; speedup 1.0000x reference)
//
#include <hip/hip_runtime.h>
#include <math.h>

// FlowLayer: 2 steps of manifold (S^2) graph heat flow.
// N=50000 nodes, C=16, D=3, E=1.6M edges.
//
// R25 = ATOMIC CSR build (replaces lhist/partial2/scan1A/boffL/pos
// machinery) + flowp reverted to proven R22 structure (56.0us).
//
// Build insight: slot order within a CSR row is IRRELEVANT (any
// permutation sums the same). So deterministic rank machinery is waste:
//   degree (atomicAdd no-return, 200KB L2) -> scanP (padded shfl-scan)
//   -> scanF (finalize row_start + cursor copy + f32->f16x4 convert)
//   -> fillA (slot = atomicAdd(&cursor[snd],1) + scattered 4B store).
// Deletes lhist (~40us), partial2/boffL/pos traffic (~12MB), chunk loops.
//
// flowp history (FROZEN at R22 form): R20 bytes -65% -> -7%; R22 VALU
// -11% -> -2%; R24 dual-wave TLP x2 -> +15% WORSE (sync+prologue costs).
// Floor ~56us is none of {bytes, VALU, TLP}; best model: TA request-beat
// throughput on divergent gathers. No source lever found in 5 attempts.
// R18 lesson: no aggregate locals in flowp. R20 lesson: alignment beats
// bytes (8B f16x4 records, one dwordx2 per gather).
//
// NOTE: |u|^2 MUST be computed from u's components (not 1-cs^2): near
// antipodal pairs 1-cs^2 cancels catastrophically -> rsq explodes (R5 bug).

constexpr float EPS64F = 2.2204460492503131e-16f;  // np.float64 eps
constexpr float PI_F   = 3.14159265358979323846f;

typedef int      vi4 __attribute__((ext_vector_type(4)));
typedef float    vf4 __attribute__((ext_vector_type(4)));
typedef float    vf2 __attribute__((ext_vector_type(2)));
typedef _Float16 vh4 __attribute__((ext_vector_type(4)));

// ---------------- CSR build (atomic, order-free) ----------------

// degree: fire-and-forget atomics into deg[N] (200KB, L2-resident).
__global__ __launch_bounds__(256) void degree_kernel(
    const vi4* __restrict__ snd4, int* __restrict__ deg,
    const int* __restrict__ snd, int E) {
  int E4 = E >> 2;
  for (int g = blockIdx.x * 256 + threadIdx.x; g < E4; g += gridDim.x * 256) {
    vi4 s = __builtin_nontemporal_load(&snd4[g]);
    atomicAdd(&deg[s.x], 1);
    atomicAdd(&deg[s.y], 1);
    atomicAdd(&deg[s.z], 1);
    atomicAdd(&deg[s.w], 1);
  }
  if (blockIdx.x == 0 && threadIdx.x == 0) {
    for (int e = E4 << 2; e < E; ++e) atomicAdd(&deg[snd[e]], 1);
  }
}

// scanP: tile shfl-scan of PAD-8 degrees -> tile-local exclusive
// row_start + tile totals (<=64 tiles of 1024).
__global__ __launch_bounds__(1024) void scanP_kernel(
    const int* __restrict__ deg, int* __restrict__ row_start,
    int* __restrict__ btot, int N) {
  __shared__ int wsum[16];
  int tid = threadIdx.x;
  int lane = tid & 63, wave = tid >> 6;
  int i = blockIdx.x * 1024 + tid;
  int vpad = (i < N) ? ((deg[i] + 7) & ~7) : 0;  // padded degree (PAD 8)
  int incl = vpad;
  #pragma unroll
  for (int off = 1; off < 64; off <<= 1) {
    int t = __shfl_up(incl, off, 64);
    if (lane >= off) incl += t;
  }
  if (lane == 63) wsum[wave] = incl;
  __syncthreads();
  if (wave == 0 && lane < 16) {
    int wincl = wsum[lane];
    #pragma unroll
    for (int off = 1; off < 16; off <<= 1) {
      int t = __shfl_up(wincl, off, 64);
      if (lane >= off) wincl += t;
    }
    wsum[lane] = wincl;
  }
  __syncthreads();
  int woff = (wave > 0) ? wsum[wave - 1] : 0;
  if (i < N) row_start[i] = woff + incl - vpad;  // tile-local exclusive
  if (tid == 0) btot[blockIdx.x] = wsum[15];
}

// scanF: wave-scan of <=64 tile totals -> finalize row_start; init cursor
// copy; fused nodes(f32 [node][c][3]) -> nodes_h4 (f16x4 8B [node*16+c]).
__global__ __launch_bounds__(256) void scanF_kernel(
    int* __restrict__ row_start, int* __restrict__ cursor,
    const int* __restrict__ btot, const float* __restrict__ nodes,
    vh4* __restrict__ nodes_h4, int N, int nb) {
  __shared__ int bsh[64];
  int tid = threadIdx.x;
  if (tid < 64) {
    int v = (tid < nb) ? btot[tid] : 0;
    int incl = v;
    #pragma unroll
    for (int off = 1; off < 64; off <<= 1) {
      int t = __shfl_up(incl, off, 64);
      if (tid >= off) incl += t;
    }
    bsh[tid] = incl - v;  // exclusive tile offset
    if (blockIdx.x == 0 && tid == 63) row_start[N] = incl;  // padded total
  }
  __syncthreads();
  int i = blockIdx.x * 256 + tid;
  if (i < N) {
    int rs = row_start[i] + bsh[i >> 10];
    row_start[i] = rs;
    cursor[i] = rs;
  }
  // fused f32 -> f16x4 conversion: N*16 records (coalesced 12B reads / 8B
  // writes across consecutive threads).
  int total = N * 16;
  for (int idx = blockIdx.x * 256 + tid; idx < total; idx += gridDim.x * 256) {
    const float* s = nodes + idx * 3;
    vh4 h = {(_Float16)s[0], (_Float16)s[1], (_Float16)s[2], (_Float16)0.f};
    nodes_h4[idx] = h;
  }
}

// fillA: slot = atomicAdd(&cursor[snd],1) (order-free rank); scattered 4B
// store packs (w 16-bit fixed << 16 | rcv16). Pad slots (row tails) stay
// zero from the memset (w=0, rcv=0).
__global__ __launch_bounds__(256) void fillA_kernel(
    const vi4* __restrict__ snd4, const vi4* __restrict__ rcv4,
    const vf4* __restrict__ ew4, int* __restrict__ cursor,
    int* __restrict__ pair, const int* __restrict__ snd,
    const int* __restrict__ rcv, const float* __restrict__ ew, int E) {
  int E4 = E >> 2;
  for (int g = blockIdx.x * 256 + threadIdx.x; g < E4; g += gridDim.x * 256) {
    vi4 s = __builtin_nontemporal_load(&snd4[g]);
    vi4 r = __builtin_nontemporal_load(&rcv4[g]);
    vf4 w = __builtin_nontemporal_load(&ew4[g]);
    int p0 = atomicAdd(&cursor[s.x], 1);
    int p1 = atomicAdd(&cursor[s.y], 1);
    int p2 = atomicAdd(&cursor[s.z], 1);
    int p3 = atomicAdd(&cursor[s.w], 1);
    pair[p0] = (int)(((unsigned)(int)fmaf(w.x, 65535.f, 0.5f) << 16) | (unsigned)r.x);
    pair[p1] = (int)(((unsigned)(int)fmaf(w.y, 65535.f, 0.5f) << 16) | (unsigned)r.y);
    pair[p2] = (int)(((unsigned)(int)fmaf(w.z, 65535.f, 0.5f) << 16) | (unsigned)r.z);
    pair[p3] = (int)(((unsigned)(int)fmaf(w.w, 65535.f, 0.5f) << 16) | (unsigned)r.w);
  }
  if (blockIdx.x == 0 && threadIdx.x == 0) {
    for (int e = E4 << 2; e < E; ++e) {  // edge tail
      int p = atomicAdd(&cursor[snd[e]], 1);
      pair[p] = (int)(((unsigned)(int)fmaf(ew[e], 65535.f, 0.5f) << 16) | (unsigned)rcv[e]);
    }
  }
}

// ---------------- flow (R22 structure, FROZEN) ----------------

__device__ __forceinline__ void edge_accum_pk(
    vf2 p0, vf2 p1, vf2 p2, vf2 q0, vf2 q1, vf2 q2, vf2 w,
    vf2& a0, vf2& a1, vf2& a2) {
  vf2 cs = p0 * q0 + p1 * q1 + p2 * q2;
  cs = __builtin_elementwise_min(vf2{1.f, 1.f},
       __builtin_elementwise_max(vf2{-1.f, -1.f}, cs));
  vf2 u0 = q0 - cs * p0;
  vf2 u1 = q1 - cs * p1;
  vf2 u2 = q2 - cs * p2;
  // |u|^2 from components (R5 lesson)
  vf2 un2 = __builtin_elementwise_max(u0 * u0 + u1 * u1 + u2 * u2,
                                      vf2{1e-24f, 1e-24f});
  // acos via A&S 4.4.45 (|err| <= 6.7e-5; output threshold is 2e-2)
  vf2 ax = __builtin_elementwise_abs(cs);
  vf2 s = __builtin_elementwise_sqrt(vf2{1.f, 1.f} - ax);
  vf2 poly = ((ax * -0.0187293f + 0.0742610f) * ax - 0.2121144f) * ax
             + 1.5707288f;
  vf2 th = s * poly;
  vf2 theta;
  theta.x = (cs.x >= 0.0f) ? th.x : (PI_F - th.x);
  theta.y = (cs.y >= 0.0f) ? th.y : (PI_F - th.y);
  vf2 rsq;
  rsq.x = __builtin_amdgcn_rsqf(un2.x);
  rsq.y = __builtin_amdgcn_rsqf(un2.y);
  vf2 coef = w * theta * rsq;
  a0 += coef * u0;
  a1 += coef * u1;
  a2 += coef * u2;
}

__device__ __forceinline__ void node_step(
    float a0, float a1, float a2, float ws, float p0, float p1, float p2,
    float ts, float dsv, float& y0, float& y1, float& y2) {
  // v_lap = -agg/deg; nrm/scale sign-invariant; -(v_lap*scale)*t = +g*scale*t
  float invdg = __builtin_amdgcn_rcpf(ws + 1e-12f);
  float g0 = a0 * invdg, g1 = a1 * invdg, g2 = a2 * invdg;
  float nrm = sqrtf(fmaf(g0, g0, fmaf(g1, g1, g2 * g2)) + EPS64F);
  float tch = ts * ts * 0.5f;  // t_sqrt^2 / N_STEPS
  float dch = dsv * dsv;
  float alp = __builtin_amdgcn_rcpf(1.0f + __expf(dch - nrm));  // sigmoid
  float scale = (nrm * alp <= 1.0f) ? alp : __builtin_amdgcn_rcpf(nrm);
  float f = scale * tch;
  float v0 = g0 * f, v1 = g1 * f, v2 = g2 * f;
  float nv = sqrtf(fmaf(v0, v0, fmaf(v1, v1, v2 * v2)));
  float cn = __cosf(nv);
  float sc = (nv > 1e-20f) ? (__sinf(nv) * __builtin_amdgcn_rcpf(nv)) : 1.0f;
  float t0 = fmaf(cn, p0, sc * v0);
  float t1 = fmaf(cn, p1, sc * v1);
  float t2 = fmaf(cn, p2, sc * v2);
  float inv = __builtin_amdgcn_rsqf(fmaf(t0, t0, fmaf(t1, t1, t2 * t2)));
  y0 = t0 * inv; y1 = t1 * inv; y2 = t2 * inv;
}

// Wave per node; lane = k*16+c; rows padded to 8 -> no guards: pads are
// (w=0, rcv=0) entries, always in-bounds. 8 edges/iter: lane k handles
// edges {j+k, j+4+k} as one vf2 pair.
// pair entry: 4B (w16fix<<16 | rcv16). q gather: ONE dwordx2 from f16x4
// records xh4[rcv*16+c]. p from f32 pf (nodes step1, d_out step2).
// Writes: of (f32, always) + oh4 (f16x4, step1 only). All math f32.
__global__ __launch_bounds__(256, 8) void flowp_kernel(
    const vh4* __restrict__ xh4, const float* __restrict__ pf,
    const int* __restrict__ row_start, const int* __restrict__ pair,
    const float* __restrict__ tsq, const float* __restrict__ dsq,
    float* __restrict__ of, vh4* __restrict__ oh4, int N) {
  int node = blockIdx.x * 4 + (threadIdx.x >> 6);
  if (node >= N) return;
  int lane = threadIdx.x & 63;
  int c = lane & 15;
  int k = lane >> 4;
  int c3 = c * 3;
  int beg = row_start[node];
  int end = row_start[node + 1];
  int ip = node * 48 + c3;
  float ps0 = pf[ip], ps1 = pf[ip + 1], ps2 = pf[ip + 2];
  vf2 p0 = {ps0, ps0}, p1 = {ps1, ps1}, p2 = {ps2, ps2};
  vf2 a0 = {0.f, 0.f}, a1 = {0.f, 0.f}, a2 = {0.f, 0.f}, wsv = {0.f, 0.f};
  const vh4* __restrict__ xc = xh4 + c;  // hoisted channel base
  int iters = (end - beg) >> 3;  // exact (rows padded to 8)
  int j = beg + k;
  constexpr float WS = 1.0f / 65535.0f;
  #pragma unroll 2
  for (int t = 0; t < iters; ++t, j += 8) {
    int e0 = pair[j];
    int e1 = pair[j + 4];
    float w0 = (float)((unsigned)e0 >> 16) * WS;
    float w1 = (float)((unsigned)e1 >> 16) * WS;
    vh4 qva = xc[(e0 & 0xFFFF) << 4];
    vh4 qvb = xc[(e1 & 0xFFFF) << 4];
    float qa0 = (float)qva.x, qa1 = (float)qva.y, qa2 = (float)qva.z;
    float qb0 = (float)qvb.x, qb1 = (float)qvb.y, qb2 = (float)qvb.z;
    vf2 wA = {w0, w1};
    edge_accum_pk(p0, p1, p2, vf2{qa0, qb0}, vf2{qa1, qb1},
                  vf2{qa2, qb2}, wA, a0, a1, a2);
    wsv += wA;
  }
  float A0 = a0.x + a0.y, A1 = a1.x + a1.y, A2 = a2.x + a2.y;
  float ws = wsv.x + wsv.y;
  A0 += __shfl_xor(A0, 16); A1 += __shfl_xor(A1, 16);
  A2 += __shfl_xor(A2, 16); ws += __shfl_xor(ws, 16);
  A0 += __shfl_xor(A0, 32); A1 += __shfl_xor(A1, 32);
  A2 += __shfl_xor(A2, 32); ws += __shfl_xor(ws, 32);
  if (k == 0) {
    float y0, y1, y2;
    node_step(A0, A1, A2, ws, ps0, ps1, ps2, tsq[c], dsq[c], y0, y1, y2);
    of[ip] = y0; of[ip + 1] = y1; of[ip + 2] = y2;
    if (oh4) {
      vh4 h = {(_Float16)y0, (_Float16)y1, (_Float16)y2, (_Float16)0.f};
      oh4[node * 16 + c] = h;
    }
  }
}

static inline size_t al16(size_t x) { return (x + 15) & ~(size_t)15; }

extern "C" void kernel_launch(void* const* d_in, const int* in_sizes, int n_in,
                              void* d_out, int out_size, void* d_ws, size_t ws_size,
                              hipStream_t stream) {
  const float* nodes = (const float*)d_in[0];  // [N,16,3]
  const float* ew    = (const float*)d_in[1];  // [E]
  const float* tsq   = (const float*)d_in[2];  // [16]
  const float* dsq   = (const float*)d_in[3];  // [16]
  const int*   snd   = (const int*)d_in[4];    // [E]
  const int*   rcv   = (const int*)d_in[5];    // [E]
  float* out = (float*)d_out;

  int E = in_sizes[1];
  int N = in_sizes[0] / 48;  // rcv16 packing assumes N < 65536

  // workspace (~21MB): row_start[N+8] | cursor[N] | pair 4B [padN] |
  //   deg[N] (adjacent to pair -> one memset zeroes both) |
  //   nodes_h4 (6.4M) | xtmp_h4 (6.4M)
  size_t padN  = (size_t)E + 7 * (size_t)N + 64;  // >= pad8 total + slack
  size_t rsB   = al16((size_t)(N + 8) * 4);
  size_t curB  = al16((size_t)N * 4);
  size_t pairB = al16(padN * 4);
  size_t degB  = al16((size_t)N * 4 + 256);       // +64 ints btot tail
  size_t xh4B  = al16((size_t)N * 16 * 8);        // one f16x4 buffer

  char* base = (char*)d_ws;
  int* row_start = (int*)base;
  int* cursor    = (int*)(base + rsB);
  int* pair      = (int*)(base + rsB + curB);
  int* deg       = (int*)(base + rsB + curB + pairB);
  int* btot      = deg + N;                       // inside degB region
  vh4* nodes_h4  = (vh4*)(base + rsB + curB + pairB + degB);
  vh4* xtmp_h4   = (vh4*)(base + rsB + curB + pairB + degB + xh4B);

  int E4  = E >> 2;
  int nb  = (N + 1023) / 1024;   // tiles (<=64 required; 49 @ N=50K)
  int nb2 = (N + 255) / 256;
  int egb = (E4 + 255) / 256;
  int nfb = (N + 3) / 4;

  // zero pair (pad slots = (w=0,rcv=0)) AND deg/btot in one memset
  hipMemsetAsync(pair, 0, pairB + degB, stream);
  degree_kernel<<<egb, 256, 0, stream>>>((const vi4*)snd, deg, snd, E);
  scanP_kernel<<<nb, 1024, 0, stream>>>(deg, row_start, btot, N);
  scanF_kernel<<<nb2, 256, 0, stream>>>(row_start, cursor, btot,
                                        nodes, nodes_h4, N, nb);
  fillA_kernel<<<egb, 256, 0, stream>>>((const vi4*)snd, (const vi4*)rcv,
                                        (const vf4*)ew, cursor, pair,
                                        snd, rcv, ew, E);

  // step1: p=nodes(f32), q=nodes_h4 -> writes out(f32 scratch) + xtmp_h4
  // step2: p=out(f32),   q=xtmp_h4  -> overwrites out (final)
  flowp_kernel<<<nfb, 256, 0, stream>>>(nodes_h4, nodes, row_start, pair,
                                        tsq, dsq, out, xtmp_h4, N);
  flowp_kernel<<<nfb, 256, 0, stream>>>(xtmp_h4, out, row_start, pair,
                                        tsq, dsq, out, nullptr, N);
}

// Round 8
// 279.839 us; speedup vs baseline: 1.3436x; 1.3436x over previous
//
#include <hip/hip_runtime.h>
#include <math.h>

// FlowLayer: 2 steps of manifold (S^2) graph heat flow.
// N=50000 nodes, C=16, D=3, E=1.6M edges.
//
// R26 = recombination of the two best-measured halves:
//  - BUILD: R24's deterministic counting-sort build VERBATIM (residual
//    155.9us measured): memset / lhist / scan1A(pad8) / scanCD(+f16
//    convert) / fill(4B pair, w 16-bit fixed). R25's atomic fillA was
//    catastrophic (140us, VALUBusy 0.3% -- atomicAdd-with-return round
//    trips serialize; 99MB write-amp from 8 XCDs dirtying every line).
//  - FLOW: R22's single-wave flowp (56.0us/step measured), w16fix decode
//    (absmax margin: f16-w hit 0.0176; w16fix gives 0.0156), nontemporal
//    pair loads (stream 6.7MB past L2, keep L2 for xh4 gathers).
// flowp floor ~56us is a TA request-beat floor on divergent gathers:
// bytes -65% -> -7% (R20/R21); VALU -11% -> -2% (R22); TLP x2 -> worse
// (R24); atomics -> disaster (R25). FROZEN.
// R18 lesson: no aggregate locals in flowp. R20 lesson: alignment beats
// bytes (8B f16x4 records, one dwordx2 per gather).
//
// NOTE: |u|^2 MUST be computed from u's components (not 1-cs^2): near
// antipodal pairs 1-cs^2 cancels catastrophically -> rsq explodes (R5 bug).

constexpr float EPS64F = 2.2204460492503131e-16f;  // np.float64 eps
constexpr float PI_F   = 3.14159265358979323846f;
constexpr int   SR_BITS = 14;                 // 16384-node subranges (64KB LDS)
constexpr int   CH_BITS = 15;                 // 32768-edge chunks

typedef int      vi4 __attribute__((ext_vector_type(4)));
typedef float    vf4 __attribute__((ext_vector_type(4)));
typedef float    vf2 __attribute__((ext_vector_type(2)));
typedef _Float16 vh4 __attribute__((ext_vector_type(4)));

// ---------------- CSR build (R24 deterministic, proven) ----------------

// LDS histogram: block (c = blockIdx.x, s = blockIdx.y).
__global__ __launch_bounds__(256) void lhist_kernel(
    const int* __restrict__ snd, unsigned char* __restrict__ pos,
    unsigned char* __restrict__ partial2, int E, int NC) {
  __shared__ int h[1 << SR_BITS];
  int tid = threadIdx.x;
  int c = blockIdx.x, s = blockIdx.y;
  for (int i = tid; i < (1 << SR_BITS); i += 256) h[i] = 0;
  __syncthreads();
  int base = c << CH_BITS;
  int cnt = min(1 << CH_BITS, E - base);
  int s0 = s << SR_BITS;
  const vi4* snd4 = (const vi4*)(snd + base);  // base is 32768-aligned
  int cnt4 = cnt >> 2;
  for (int i = tid; i < cnt4; i += 256) {
    vi4 sv = snd4[i];
    int e = base + (i << 2);
    int v;
    v = sv.x - s0; if ((unsigned)v < (1u << SR_BITS)) pos[e]     = (unsigned char)atomicAdd(&h[v], 1);
    v = sv.y - s0; if ((unsigned)v < (1u << SR_BITS)) pos[e + 1] = (unsigned char)atomicAdd(&h[v], 1);
    v = sv.z - s0; if ((unsigned)v < (1u << SR_BITS)) pos[e + 2] = (unsigned char)atomicAdd(&h[v], 1);
    v = sv.w - s0; if ((unsigned)v < (1u << SR_BITS)) pos[e + 3] = (unsigned char)atomicAdd(&h[v], 1);
  }
  if (tid == 0) {  // chunk tail (cnt % 4)
    for (int i = cnt4 << 2; i < cnt; ++i) {
      int v = snd[base + i] - s0;
      if ((unsigned)v < (1u << SR_BITS))
        pos[base + i] = (unsigned char)atomicAdd(&h[v], 1);
    }
  }
  __syncthreads();
  unsigned char* dst = partial2 + ((size_t)(s * NC + c) << SR_BITS);
  for (int i = tid; i < (1 << SR_BITS); i += 256)
    dst[i] = (unsigned char)h[i];
}

// Fused scan1+scanA with row padding (PAD 8): per-node exclusive fold over
// chunks (boffL uchar) -> degree; tile shfl-scan of padded degree ->
// tile-local exclusive row_start + tile totals.
__global__ __launch_bounds__(1024) void scan1A_kernel(
    const unsigned char* __restrict__ partial2, unsigned char* __restrict__ boffL,
    int* __restrict__ row_start, int* __restrict__ btot, int N, int NC) {
  __shared__ int wsum[16];
  int tid = threadIdx.x;
  int lane = tid & 63, wave = tid >> 6;
  int i = blockIdx.x * 1024 + tid;
  int vpad = 0;
  if (i < N) {
    int s = i >> SR_BITS, lv = i & ((1 << SR_BITS) - 1);
    int run = 0;
    for (int c = 0; c < NC; ++c) {
      int t = partial2[((size_t)(s * NC + c) << SR_BITS) + lv];
      boffL[(size_t)c * N + i] = (unsigned char)run;  // run <= degree <= ~80
      run += t;
    }
    vpad = (run + 7) & ~7;  // padded degree (PAD 8)
  }
  int incl = vpad;
  #pragma unroll
  for (int off = 1; off < 64; off <<= 1) {
    int t = __shfl_up(incl, off, 64);
    if (lane >= off) incl += t;
  }
  if (lane == 63) wsum[wave] = incl;
  __syncthreads();
  if (wave == 0 && lane < 16) {
    int wincl = wsum[lane];
    #pragma unroll
    for (int off = 1; off < 16; off <<= 1) {
      int t = __shfl_up(wincl, off, 64);
      if (lane >= off) wincl += t;
    }
    wsum[lane] = wincl;
  }
  __syncthreads();
  int woff = (wave > 0) ? wsum[wave - 1] : 0;
  if (i < N) row_start[i] = woff + incl - vpad;  // tile-local exclusive
  if (tid == 0) btot[blockIdx.x] = wsum[15];
}

// scanCD: wave-scan of <=64 tile totals -> finalize row_start. Fused:
// nodes(f32 [node][c][3]) -> nodes_h4 (f16x4 8B [node*16+c]) conversion.
__global__ __launch_bounds__(256) void scanCD_kernel(
    int* __restrict__ row_start, const int* __restrict__ btot,
    const float* __restrict__ nodes, vh4* __restrict__ nodes_h4,
    int N, int nb) {
  __shared__ int bsh[64];
  int tid = threadIdx.x;
  if (tid < 64) {
    int v = (tid < nb) ? btot[tid] : 0;
    int incl = v;
    #pragma unroll
    for (int off = 1; off < 64; off <<= 1) {
      int t = __shfl_up(incl, off, 64);
      if (tid >= off) incl += t;
    }
    bsh[tid] = incl - v;  // exclusive tile offset
    if (blockIdx.x == 0 && tid == 63) row_start[N] = incl;  // padded total
  }
  __syncthreads();
  int i = blockIdx.x * 256 + tid;
  if (i < N) row_start[i] = row_start[i] + bsh[i >> 10];
  // fused f32 -> f16x4 conversion: N*16 records (coalesced 12B reads / 8B
  // writes across consecutive threads).
  int total = N * 16;
  for (int idx = blockIdx.x * 256 + tid; idx < total; idx += gridDim.x * 256) {
    const float* s = nodes + idx * 3;
    vh4 h = {(_Float16)s[0], (_Float16)s[1], (_Float16)s[2], (_Float16)0.f};
    nodes_h4[idx] = h;
  }
}

// Atomic-free fill: slot = row_start[snd] + boffL[chunk][snd] + pos[e];
// packs 4B (w 16-bit fixed << 16 | rcv16). Pad slots stay zero from the
// memset (w=0, rcv=0). row_start + chunk's boffL slice are L2-resident.
__global__ __launch_bounds__(256) void fill_kernel(
    const vi4* __restrict__ snd4, const vi4* __restrict__ rcv4,
    const vf4* __restrict__ ew4, const unsigned char* __restrict__ pos,
    const unsigned char* __restrict__ boffL, const int* __restrict__ row_start,
    int* __restrict__ pair,
    const int* __restrict__ snd, const int* __restrict__ rcv,
    const float* __restrict__ ew, int N, int E) {
  int tid = threadIdx.x;
  int E4 = E >> 2;
  #pragma unroll
  for (int gg = 0; gg < 2; ++gg) {
    int g = blockIdx.x * 512 + gg * 256 + tid;
    if (g < E4) {
      int e = g << 2;
      const unsigned char* bc = boffL + (size_t)(e >> CH_BITS) * N;  // same chunk e..e+3
      vi4 s = __builtin_nontemporal_load(&snd4[g]);
      vi4 r = __builtin_nontemporal_load(&rcv4[g]);
      vf4 w = __builtin_nontemporal_load(&ew4[g]);
      unsigned pb = *(const unsigned*)(pos + e);
      int rs0 = row_start[s.x] + bc[s.x];
      int rs1 = row_start[s.y] + bc[s.y];
      int rs2 = row_start[s.z] + bc[s.z];
      int rs3 = row_start[s.w] + bc[s.w];
      unsigned e0 = ((unsigned)(int)fmaf(w.x, 65535.f, 0.5f) << 16) | (unsigned)r.x;
      unsigned e1 = ((unsigned)(int)fmaf(w.y, 65535.f, 0.5f) << 16) | (unsigned)r.y;
      unsigned e2 = ((unsigned)(int)fmaf(w.z, 65535.f, 0.5f) << 16) | (unsigned)r.z;
      unsigned e3 = ((unsigned)(int)fmaf(w.w, 65535.f, 0.5f) << 16) | (unsigned)r.w;
      pair[rs0 + (pb & 255u)]         = (int)e0;
      pair[rs1 + ((pb >> 8) & 255u)]  = (int)e1;
      pair[rs2 + ((pb >> 16) & 255u)] = (int)e2;
      pair[rs3 + (pb >> 24)]          = (int)e3;
    }
  }
  if (blockIdx.x == 0 && tid == 0) {
    for (int e = E4 << 2; e < E; ++e) {  // edge tail
      int sn = snd[e];
      pair[row_start[sn] + boffL[(size_t)(e >> CH_BITS) * N + sn] + pos[e]] =
          (int)(((unsigned)(int)fmaf(ew[e], 65535.f, 0.5f) << 16) | (unsigned)rcv[e]);
    }
  }
}

// ---------------- flow (R22 structure, FROZEN) ----------------

__device__ __forceinline__ void edge_accum_pk(
    vf2 p0, vf2 p1, vf2 p2, vf2 q0, vf2 q1, vf2 q2, vf2 w,
    vf2& a0, vf2& a1, vf2& a2) {
  vf2 cs = p0 * q0 + p1 * q1 + p2 * q2;
  cs = __builtin_elementwise_min(vf2{1.f, 1.f},
       __builtin_elementwise_max(vf2{-1.f, -1.f}, cs));
  vf2 u0 = q0 - cs * p0;
  vf2 u1 = q1 - cs * p1;
  vf2 u2 = q2 - cs * p2;
  // |u|^2 from components (R5 lesson)
  vf2 un2 = __builtin_elementwise_max(u0 * u0 + u1 * u1 + u2 * u2,
                                      vf2{1e-24f, 1e-24f});
  // acos via A&S 4.4.45 (|err| <= 6.7e-5; output threshold is 2e-2)
  vf2 ax = __builtin_elementwise_abs(cs);
  vf2 s = __builtin_elementwise_sqrt(vf2{1.f, 1.f} - ax);
  vf2 poly = ((ax * -0.0187293f + 0.0742610f) * ax - 0.2121144f) * ax
             + 1.5707288f;
  vf2 th = s * poly;
  vf2 theta;
  theta.x = (cs.x >= 0.0f) ? th.x : (PI_F - th.x);
  theta.y = (cs.y >= 0.0f) ? th.y : (PI_F - th.y);
  vf2 rsq;
  rsq.x = __builtin_amdgcn_rsqf(un2.x);
  rsq.y = __builtin_amdgcn_rsqf(un2.y);
  vf2 coef = w * theta * rsq;
  a0 += coef * u0;
  a1 += coef * u1;
  a2 += coef * u2;
}

__device__ __forceinline__ void node_step(
    float a0, float a1, float a2, float ws, float p0, float p1, float p2,
    float ts, float dsv, float& y0, float& y1, float& y2) {
  // v_lap = -agg/deg; nrm/scale sign-invariant; -(v_lap*scale)*t = +g*scale*t
  float invdg = __builtin_amdgcn_rcpf(ws + 1e-12f);
  float g0 = a0 * invdg, g1 = a1 * invdg, g2 = a2 * invdg;
  float nrm = sqrtf(fmaf(g0, g0, fmaf(g1, g1, g2 * g2)) + EPS64F);
  float tch = ts * ts * 0.5f;  // t_sqrt^2 / N_STEPS
  float dch = dsv * dsv;
  float alp = __builtin_amdgcn_rcpf(1.0f + __expf(dch - nrm));  // sigmoid
  float scale = (nrm * alp <= 1.0f) ? alp : __builtin_amdgcn_rcpf(nrm);
  float f = scale * tch;
  float v0 = g0 * f, v1 = g1 * f, v2 = g2 * f;
  float nv = sqrtf(fmaf(v0, v0, fmaf(v1, v1, v2 * v2)));
  float cn = __cosf(nv);
  float sc = (nv > 1e-20f) ? (__sinf(nv) * __builtin_amdgcn_rcpf(nv)) : 1.0f;
  float t0 = fmaf(cn, p0, sc * v0);
  float t1 = fmaf(cn, p1, sc * v1);
  float t2 = fmaf(cn, p2, sc * v2);
  float inv = __builtin_amdgcn_rsqf(fmaf(t0, t0, fmaf(t1, t1, t2 * t2)));
  y0 = t0 * inv; y1 = t1 * inv; y2 = t2 * inv;
}

// Wave per node; lane = k*16+c; rows padded to 8 -> no guards: pads are
// (w=0, rcv=0) entries, always in-bounds. 8 edges/iter: lane k handles
// edges {j+k, j+4+k} as one vf2 pair.
// pair entry: 4B (w16fix<<16 | rcv16). q gather: ONE dwordx2 from f16x4
// records xh4[rcv*16+c]. p from f32 pf (nodes step1, d_out step2).
// Writes: of (f32, always) + oh4 (f16x4, step1 only). All math f32.
__global__ __launch_bounds__(256, 8) void flowp_kernel(
    const vh4* __restrict__ xh4, const float* __restrict__ pf,
    const int* __restrict__ row_start, const int* __restrict__ pair,
    const float* __restrict__ tsq, const float* __restrict__ dsq,
    float* __restrict__ of, vh4* __restrict__ oh4, int N) {
  int node = blockIdx.x * 4 + (threadIdx.x >> 6);
  if (node >= N) return;
  int lane = threadIdx.x & 63;
  int c = lane & 15;
  int k = lane >> 4;
  int c3 = c * 3;
  int beg = row_start[node];
  int end = row_start[node + 1];
  int ip = node * 48 + c3;
  float ps0 = pf[ip], ps1 = pf[ip + 1], ps2 = pf[ip + 2];
  vf2 p0 = {ps0, ps0}, p1 = {ps1, ps1}, p2 = {ps2, ps2};
  vf2 a0 = {0.f, 0.f}, a1 = {0.f, 0.f}, a2 = {0.f, 0.f}, wsv = {0.f, 0.f};
  const vh4* __restrict__ xc = xh4 + c;  // hoisted channel base
  int iters = (end - beg) >> 3;  // exact (rows padded to 8)
  int j = beg + k;
  constexpr float WS = 1.0f / 65535.0f;
  #pragma unroll 2
  for (int t = 0; t < iters; ++t, j += 8) {
    int e0 = __builtin_nontemporal_load(&pair[j]);
    int e1 = __builtin_nontemporal_load(&pair[j + 4]);
    float w0 = (float)((unsigned)e0 >> 16) * WS;
    float w1 = (float)((unsigned)e1 >> 16) * WS;
    vh4 qva = xc[(e0 & 0xFFFF) << 4];
    vh4 qvb = xc[(e1 & 0xFFFF) << 4];
    float qa0 = (float)qva.x, qa1 = (float)qva.y, qa2 = (float)qva.z;
    float qb0 = (float)qvb.x, qb1 = (float)qvb.y, qb2 = (float)qvb.z;
    vf2 wA = {w0, w1};
    edge_accum_pk(p0, p1, p2, vf2{qa0, qb0}, vf2{qa1, qb1},
                  vf2{qa2, qb2}, wA, a0, a1, a2);
    wsv += wA;
  }
  float A0 = a0.x + a0.y, A1 = a1.x + a1.y, A2 = a2.x + a2.y;
  float ws = wsv.x + wsv.y;
  A0 += __shfl_xor(A0, 16); A1 += __shfl_xor(A1, 16);
  A2 += __shfl_xor(A2, 16); ws += __shfl_xor(ws, 16);
  A0 += __shfl_xor(A0, 32); A1 += __shfl_xor(A1, 32);
  A2 += __shfl_xor(A2, 32); ws += __shfl_xor(ws, 32);
  if (k == 0) {
    float y0, y1, y2;
    node_step(A0, A1, A2, ws, ps0, ps1, ps2, tsq[c], dsq[c], y0, y1, y2);
    of[ip] = y0; of[ip + 1] = y1; of[ip + 2] = y2;
    if (oh4) {
      vh4 h = {(_Float16)y0, (_Float16)y1, (_Float16)y2, (_Float16)0.f};
      oh4[node * 16 + c] = h;
    }
  }
}

static inline size_t al16(size_t x) { return (x + 15) & ~(size_t)15; }

extern "C" void kernel_launch(void* const* d_in, const int* in_sizes, int n_in,
                              void* d_out, int out_size, void* d_ws, size_t ws_size,
                              hipStream_t stream) {
  const float* nodes = (const float*)d_in[0];  // [N,16,3]
  const float* ew    = (const float*)d_in[1];  // [E]
  const float* tsq   = (const float*)d_in[2];  // [16]
  const float* dsq   = (const float*)d_in[3];  // [16]
  const int*   snd   = (const int*)d_in[4];    // [E]
  const int*   rcv   = (const int*)d_in[5];    // [E]
  float* out = (float*)d_out;

  int E = in_sizes[1];
  int N = in_sizes[0] / 48;  // rcv16 packing assumes N < 65536

  int NS = (N + (1 << SR_BITS) - 1) >> SR_BITS;  // node subranges (4)
  int NC = (E + (1 << CH_BITS) - 1) >> CH_BITS;  // edge chunks (49)

  // workspace (~23MB): row_start[N+4] | aux(btot) | pair 4B | partial2 |
  //   boffL-region | pos(E bytes)
  // f16 carve inside partial2+boffL (13.0MB, dead before their writers):
  // xtmp_h4 [0,6.4M) by flow1 (after fill), nodes_h4 [6.4,12.8M) by scanCD
  // (disjoint from partial2 [0,3.2M) and live boffL [3.2,5.65M)).
  size_t padN  = (size_t)E + 7 * (size_t)N + 64;  // >= pad8 total + slack
  size_t rsB   = al16((size_t)(N + 4) * 4);
  size_t auxB  = 512;
  size_t pairB = al16(padN * 4);
  size_t p2B   = al16((size_t)NS * NC << SR_BITS);  // uchar
  size_t xh4B  = al16((size_t)N * 16 * 8);          // one f16x4 buffer
  size_t boffB = al16((size_t)NC * N * 4);
  if (p2B + boffB < 2 * xh4B) boffB = 2 * xh4B - p2B;  // safety

  char* base = (char*)d_ws;
  int*           row_start = (int*)base;
  int*           btot      = (int*)(base + rsB);        // [64]
  int*           pair      = (int*)(base + rsB + auxB);
  unsigned char* partial2  = (unsigned char*)(base + rsB + auxB + pairB);
  unsigned char* boffL     = partial2 + p2B;
  unsigned char* pos       = boffL + boffB;
  vh4*           xtmp_h4   = (vh4*)partial2;          // dead region after fill
  vh4*           nodes_h4  = (vh4*)(partial2 + xh4B);

  int E4  = E >> 2;
  int nb  = (N + 1023) / 1024;   // tiles (<=64 required; 49 @ N=50K)
  int nb2 = (N + 255) / 256;
  int fbk = (E4 + 511) / 512;
  int nfb = (N + 3) / 4;

  hipMemsetAsync(pair, 0, pairB, stream);  // zero pad slots (w=0, rcv=0)
  lhist_kernel<<<dim3(NC, NS), 256, 0, stream>>>(snd, pos, partial2, E, NC);
  scan1A_kernel<<<nb, 1024, 0, stream>>>(partial2, boffL, row_start, btot, N, NC);
  scanCD_kernel<<<nb2, 256, 0, stream>>>(row_start, btot, nodes, nodes_h4, N, nb);
  fill_kernel<<<fbk, 256, 0, stream>>>((const vi4*)snd, (const vi4*)rcv,
                                       (const vf4*)ew, pos, boffL, row_start,
                                       pair, snd, rcv, ew, N, E);

  // step1: p=nodes(f32), q=nodes_h4 -> writes out(f32 scratch) + xtmp_h4
  // step2: p=out(f32),   q=xtmp_h4  -> overwrites out (final)
  flowp_kernel<<<nfb, 256, 0, stream>>>(nodes_h4, nodes, row_start, pair,
                                        tsq, dsq, out, xtmp_h4, N);
  flowp_kernel<<<nfb, 256, 0, stream>>>(xtmp_h4, out, row_start, pair,
                                        tsq, dsq, out, nullptr, N);
}

// Round 9
// 269.798 us; speedup vs baseline: 1.3936x; 1.0372x over previous
//
#include <hip/hip_runtime.h>
#include <math.h>

// FlowLayer: 2 steps of manifold (S^2) graph heat flow.
// N=50000 nodes, C=16, D=3, E=1.6M edges.
//
// R27 = R26 with ONE change: flowp pair loads back to PLAIN loads.
// R26 post-mortem: nontemporal on pair evicted it from L2 -> step2
// re-fetched the whole 6.7MB stream (FETCH 102->107.7MB, flowp 56->60us).
// Everything else is the best-measured component set:
//  - BUILD (R24/R26, residual ~156us): memset / lhist / scan1A(pad8) /
//    scanCD(+f16x4 convert) / fill (4B pair, w 16-bit fixed).
//  - FLOW (R22, 56.0us/step): wave/node, pad8, 8 edges/iter vf2-packed,
//    f16x4 single-dwordx2 gathers, f32 p-base, w16fix decode.
// flowp floor ~56us: divergent-gather floor -- six falsified levers
// (bytes -65%->-7%, VALU -11%->-2%, TLP x2 worse, atomics disaster,
// SW pipeline compiler-collapsed, nontemporal worse). FROZEN.
// R18 lesson: no aggregate locals in flowp. R20 lesson: alignment beats
// bytes (8B f16x4 records, one dwordx2 per gather).
//
// NOTE: |u|^2 MUST be computed from u's components (not 1-cs^2): near
// antipodal pairs 1-cs^2 cancels catastrophically -> rsq explodes (R5 bug).

constexpr float EPS64F = 2.2204460492503131e-16f;  // np.float64 eps
constexpr float PI_F   = 3.14159265358979323846f;
constexpr int   SR_BITS = 14;                 // 16384-node subranges (64KB LDS)
constexpr int   CH_BITS = 15;                 // 32768-edge chunks

typedef int      vi4 __attribute__((ext_vector_type(4)));
typedef float    vf4 __attribute__((ext_vector_type(4)));
typedef float    vf2 __attribute__((ext_vector_type(2)));
typedef _Float16 vh4 __attribute__((ext_vector_type(4)));

// ---------------- CSR build (R24 deterministic, proven) ----------------

// LDS histogram: block (c = blockIdx.x, s = blockIdx.y).
__global__ __launch_bounds__(256) void lhist_kernel(
    const int* __restrict__ snd, unsigned char* __restrict__ pos,
    unsigned char* __restrict__ partial2, int E, int NC) {
  __shared__ int h[1 << SR_BITS];
  int tid = threadIdx.x;
  int c = blockIdx.x, s = blockIdx.y;
  for (int i = tid; i < (1 << SR_BITS); i += 256) h[i] = 0;
  __syncthreads();
  int base = c << CH_BITS;
  int cnt = min(1 << CH_BITS, E - base);
  int s0 = s << SR_BITS;
  const vi4* snd4 = (const vi4*)(snd + base);  // base is 32768-aligned
  int cnt4 = cnt >> 2;
  for (int i = tid; i < cnt4; i += 256) {
    vi4 sv = snd4[i];
    int e = base + (i << 2);
    int v;
    v = sv.x - s0; if ((unsigned)v < (1u << SR_BITS)) pos[e]     = (unsigned char)atomicAdd(&h[v], 1);
    v = sv.y - s0; if ((unsigned)v < (1u << SR_BITS)) pos[e + 1] = (unsigned char)atomicAdd(&h[v], 1);
    v = sv.z - s0; if ((unsigned)v < (1u << SR_BITS)) pos[e + 2] = (unsigned char)atomicAdd(&h[v], 1);
    v = sv.w - s0; if ((unsigned)v < (1u << SR_BITS)) pos[e + 3] = (unsigned char)atomicAdd(&h[v], 1);
  }
  if (tid == 0) {  // chunk tail (cnt % 4)
    for (int i = cnt4 << 2; i < cnt; ++i) {
      int v = snd[base + i] - s0;
      if ((unsigned)v < (1u << SR_BITS))
        pos[base + i] = (unsigned char)atomicAdd(&h[v], 1);
    }
  }
  __syncthreads();
  unsigned char* dst = partial2 + ((size_t)(s * NC + c) << SR_BITS);
  for (int i = tid; i < (1 << SR_BITS); i += 256)
    dst[i] = (unsigned char)h[i];
}

// Fused scan1+scanA with row padding (PAD 8): per-node exclusive fold over
// chunks (boffL uchar) -> degree; tile shfl-scan of padded degree ->
// tile-local exclusive row_start + tile totals.
__global__ __launch_bounds__(1024) void scan1A_kernel(
    const unsigned char* __restrict__ partial2, unsigned char* __restrict__ boffL,
    int* __restrict__ row_start, int* __restrict__ btot, int N, int NC) {
  __shared__ int wsum[16];
  int tid = threadIdx.x;
  int lane = tid & 63, wave = tid >> 6;
  int i = blockIdx.x * 1024 + tid;
  int vpad = 0;
  if (i < N) {
    int s = i >> SR_BITS, lv = i & ((1 << SR_BITS) - 1);
    int run = 0;
    for (int c = 0; c < NC; ++c) {
      int t = partial2[((size_t)(s * NC + c) << SR_BITS) + lv];
      boffL[(size_t)c * N + i] = (unsigned char)run;  // run <= degree <= ~80
      run += t;
    }
    vpad = (run + 7) & ~7;  // padded degree (PAD 8)
  }
  int incl = vpad;
  #pragma unroll
  for (int off = 1; off < 64; off <<= 1) {
    int t = __shfl_up(incl, off, 64);
    if (lane >= off) incl += t;
  }
  if (lane == 63) wsum[wave] = incl;
  __syncthreads();
  if (wave == 0 && lane < 16) {
    int wincl = wsum[lane];
    #pragma unroll
    for (int off = 1; off < 16; off <<= 1) {
      int t = __shfl_up(wincl, off, 64);
      if (lane >= off) wincl += t;
    }
    wsum[lane] = wincl;
  }
  __syncthreads();
  int woff = (wave > 0) ? wsum[wave - 1] : 0;
  if (i < N) row_start[i] = woff + incl - vpad;  // tile-local exclusive
  if (tid == 0) btot[blockIdx.x] = wsum[15];
}

// scanCD: wave-scan of <=64 tile totals -> finalize row_start. Fused:
// nodes(f32 [node][c][3]) -> nodes_h4 (f16x4 8B [node*16+c]) conversion.
__global__ __launch_bounds__(256) void scanCD_kernel(
    int* __restrict__ row_start, const int* __restrict__ btot,
    const float* __restrict__ nodes, vh4* __restrict__ nodes_h4,
    int N, int nb) {
  __shared__ int bsh[64];
  int tid = threadIdx.x;
  if (tid < 64) {
    int v = (tid < nb) ? btot[tid] : 0;
    int incl = v;
    #pragma unroll
    for (int off = 1; off < 64; off <<= 1) {
      int t = __shfl_up(incl, off, 64);
      if (tid >= off) incl += t;
    }
    bsh[tid] = incl - v;  // exclusive tile offset
    if (blockIdx.x == 0 && tid == 63) row_start[N] = incl;  // padded total
  }
  __syncthreads();
  int i = blockIdx.x * 256 + tid;
  if (i < N) row_start[i] = row_start[i] + bsh[i >> 10];
  // fused f32 -> f16x4 conversion: N*16 records (coalesced 12B reads / 8B
  // writes across consecutive threads).
  int total = N * 16;
  for (int idx = blockIdx.x * 256 + tid; idx < total; idx += gridDim.x * 256) {
    const float* s = nodes + idx * 3;
    vh4 h = {(_Float16)s[0], (_Float16)s[1], (_Float16)s[2], (_Float16)0.f};
    nodes_h4[idx] = h;
  }
}

// Atomic-free fill: slot = row_start[snd] + boffL[chunk][snd] + pos[e];
// packs 4B (w 16-bit fixed << 16 | rcv16). Pad slots stay zero from the
// memset (w=0, rcv=0). row_start + chunk's boffL slice are L2-resident.
__global__ __launch_bounds__(256) void fill_kernel(
    const vi4* __restrict__ snd4, const vi4* __restrict__ rcv4,
    const vf4* __restrict__ ew4, const unsigned char* __restrict__ pos,
    const unsigned char* __restrict__ boffL, const int* __restrict__ row_start,
    int* __restrict__ pair,
    const int* __restrict__ snd, const int* __restrict__ rcv,
    const float* __restrict__ ew, int N, int E) {
  int tid = threadIdx.x;
  int E4 = E >> 2;
  #pragma unroll
  for (int gg = 0; gg < 2; ++gg) {
    int g = blockIdx.x * 512 + gg * 256 + tid;
    if (g < E4) {
      int e = g << 2;
      const unsigned char* bc = boffL + (size_t)(e >> CH_BITS) * N;  // same chunk e..e+3
      vi4 s = __builtin_nontemporal_load(&snd4[g]);
      vi4 r = __builtin_nontemporal_load(&rcv4[g]);
      vf4 w = __builtin_nontemporal_load(&ew4[g]);
      unsigned pb = *(const unsigned*)(pos + e);
      int rs0 = row_start[s.x] + bc[s.x];
      int rs1 = row_start[s.y] + bc[s.y];
      int rs2 = row_start[s.z] + bc[s.z];
      int rs3 = row_start[s.w] + bc[s.w];
      unsigned e0 = ((unsigned)(int)fmaf(w.x, 65535.f, 0.5f) << 16) | (unsigned)r.x;
      unsigned e1 = ((unsigned)(int)fmaf(w.y, 65535.f, 0.5f) << 16) | (unsigned)r.y;
      unsigned e2 = ((unsigned)(int)fmaf(w.z, 65535.f, 0.5f) << 16) | (unsigned)r.z;
      unsigned e3 = ((unsigned)(int)fmaf(w.w, 65535.f, 0.5f) << 16) | (unsigned)r.w;
      pair[rs0 + (pb & 255u)]         = (int)e0;
      pair[rs1 + ((pb >> 8) & 255u)]  = (int)e1;
      pair[rs2 + ((pb >> 16) & 255u)] = (int)e2;
      pair[rs3 + (pb >> 24)]          = (int)e3;
    }
  }
  if (blockIdx.x == 0 && tid == 0) {
    for (int e = E4 << 2; e < E; ++e) {  // edge tail
      int sn = snd[e];
      pair[row_start[sn] + boffL[(size_t)(e >> CH_BITS) * N + sn] + pos[e]] =
          (int)(((unsigned)(int)fmaf(ew[e], 65535.f, 0.5f) << 16) | (unsigned)rcv[e]);
    }
  }
}

// ---------------- flow (R22 structure, FROZEN) ----------------

__device__ __forceinline__ void edge_accum_pk(
    vf2 p0, vf2 p1, vf2 p2, vf2 q0, vf2 q1, vf2 q2, vf2 w,
    vf2& a0, vf2& a1, vf2& a2) {
  vf2 cs = p0 * q0 + p1 * q1 + p2 * q2;
  cs = __builtin_elementwise_min(vf2{1.f, 1.f},
       __builtin_elementwise_max(vf2{-1.f, -1.f}, cs));
  vf2 u0 = q0 - cs * p0;
  vf2 u1 = q1 - cs * p1;
  vf2 u2 = q2 - cs * p2;
  // |u|^2 from components (R5 lesson)
  vf2 un2 = __builtin_elementwise_max(u0 * u0 + u1 * u1 + u2 * u2,
                                      vf2{1e-24f, 1e-24f});
  // acos via A&S 4.4.45 (|err| <= 6.7e-5; output threshold is 2e-2)
  vf2 ax = __builtin_elementwise_abs(cs);
  vf2 s = __builtin_elementwise_sqrt(vf2{1.f, 1.f} - ax);
  vf2 poly = ((ax * -0.0187293f + 0.0742610f) * ax - 0.2121144f) * ax
             + 1.5707288f;
  vf2 th = s * poly;
  vf2 theta;
  theta.x = (cs.x >= 0.0f) ? th.x : (PI_F - th.x);
  theta.y = (cs.y >= 0.0f) ? th.y : (PI_F - th.y);
  vf2 rsq;
  rsq.x = __builtin_amdgcn_rsqf(un2.x);
  rsq.y = __builtin_amdgcn_rsqf(un2.y);
  vf2 coef = w * theta * rsq;
  a0 += coef * u0;
  a1 += coef * u1;
  a2 += coef * u2;
}

__device__ __forceinline__ void node_step(
    float a0, float a1, float a2, float ws, float p0, float p1, float p2,
    float ts, float dsv, float& y0, float& y1, float& y2) {
  // v_lap = -agg/deg; nrm/scale sign-invariant; -(v_lap*scale)*t = +g*scale*t
  float invdg = __builtin_amdgcn_rcpf(ws + 1e-12f);
  float g0 = a0 * invdg, g1 = a1 * invdg, g2 = a2 * invdg;
  float nrm = sqrtf(fmaf(g0, g0, fmaf(g1, g1, g2 * g2)) + EPS64F);
  float tch = ts * ts * 0.5f;  // t_sqrt^2 / N_STEPS
  float dch = dsv * dsv;
  float alp = __builtin_amdgcn_rcpf(1.0f + __expf(dch - nrm));  // sigmoid
  float scale = (nrm * alp <= 1.0f) ? alp : __builtin_amdgcn_rcpf(nrm);
  float f = scale * tch;
  float v0 = g0 * f, v1 = g1 * f, v2 = g2 * f;
  float nv = sqrtf(fmaf(v0, v0, fmaf(v1, v1, v2 * v2)));
  float cn = __cosf(nv);
  float sc = (nv > 1e-20f) ? (__sinf(nv) * __builtin_amdgcn_rcpf(nv)) : 1.0f;
  float t0 = fmaf(cn, p0, sc * v0);
  float t1 = fmaf(cn, p1, sc * v1);
  float t2 = fmaf(cn, p2, sc * v2);
  float inv = __builtin_amdgcn_rsqf(fmaf(t0, t0, fmaf(t1, t1, t2 * t2)));
  y0 = t0 * inv; y1 = t1 * inv; y2 = t2 * inv;
}

// Wave per node; lane = k*16+c; rows padded to 8 -> no guards: pads are
// (w=0, rcv=0) entries, always in-bounds. 8 edges/iter: lane k handles
// edges {j+k, j+4+k} as one vf2 pair.
// pair entry: 4B (w16fix<<16 | rcv16). q gather: ONE dwordx2 from f16x4
// records xh4[rcv*16+c]. p from f32 pf (nodes step1, d_out step2).
// Writes: of (f32, always) + oh4 (f16x4, step1 only). All math f32.
// Pair loads PLAIN (R26 lesson: nontemporal evicts L2 -> step2 refetch).
__global__ __launch_bounds__(256, 8) void flowp_kernel(
    const vh4* __restrict__ xh4, const float* __restrict__ pf,
    const int* __restrict__ row_start, const int* __restrict__ pair,
    const float* __restrict__ tsq, const float* __restrict__ dsq,
    float* __restrict__ of, vh4* __restrict__ oh4, int N) {
  int node = blockIdx.x * 4 + (threadIdx.x >> 6);
  if (node >= N) return;
  int lane = threadIdx.x & 63;
  int c = lane & 15;
  int k = lane >> 4;
  int c3 = c * 3;
  int beg = row_start[node];
  int end = row_start[node + 1];
  int ip = node * 48 + c3;
  float ps0 = pf[ip], ps1 = pf[ip + 1], ps2 = pf[ip + 2];
  vf2 p0 = {ps0, ps0}, p1 = {ps1, ps1}, p2 = {ps2, ps2};
  vf2 a0 = {0.f, 0.f}, a1 = {0.f, 0.f}, a2 = {0.f, 0.f}, wsv = {0.f, 0.f};
  const vh4* __restrict__ xc = xh4 + c;  // hoisted channel base
  int iters = (end - beg) >> 3;  // exact (rows padded to 8)
  int j = beg + k;
  constexpr float WS = 1.0f / 65535.0f;
  #pragma unroll 2
  for (int t = 0; t < iters; ++t, j += 8) {
    int e0 = pair[j];
    int e1 = pair[j + 4];
    float w0 = (float)((unsigned)e0 >> 16) * WS;
    float w1 = (float)((unsigned)e1 >> 16) * WS;
    vh4 qva = xc[(e0 & 0xFFFF) << 4];
    vh4 qvb = xc[(e1 & 0xFFFF) << 4];
    float qa0 = (float)qva.x, qa1 = (float)qva.y, qa2 = (float)qva.z;
    float qb0 = (float)qvb.x, qb1 = (float)qvb.y, qb2 = (float)qvb.z;
    vf2 wA = {w0, w1};
    edge_accum_pk(p0, p1, p2, vf2{qa0, qb0}, vf2{qa1, qb1},
                  vf2{qa2, qb2}, wA, a0, a1, a2);
    wsv += wA;
  }
  float A0 = a0.x + a0.y, A1 = a1.x + a1.y, A2 = a2.x + a2.y;
  float ws = wsv.x + wsv.y;
  A0 += __shfl_xor(A0, 16); A1 += __shfl_xor(A1, 16);
  A2 += __shfl_xor(A2, 16); ws += __shfl_xor(ws, 16);
  A0 += __shfl_xor(A0, 32); A1 += __shfl_xor(A1, 32);
  A2 += __shfl_xor(A2, 32); ws += __shfl_xor(ws, 32);
  if (k == 0) {
    float y0, y1, y2;
    node_step(A0, A1, A2, ws, ps0, ps1, ps2, tsq[c], dsq[c], y0, y1, y2);
    of[ip] = y0; of[ip + 1] = y1; of[ip + 2] = y2;
    if (oh4) {
      vh4 h = {(_Float16)y0, (_Float16)y1, (_Float16)y2, (_Float16)0.f};
      oh4[node * 16 + c] = h;
    }
  }
}

static inline size_t al16(size_t x) { return (x + 15) & ~(size_t)15; }

extern "C" void kernel_launch(void* const* d_in, const int* in_sizes, int n_in,
                              void* d_out, int out_size, void* d_ws, size_t ws_size,
                              hipStream_t stream) {
  const float* nodes = (const float*)d_in[0];  // [N,16,3]
  const float* ew    = (const float*)d_in[1];  // [E]
  const float* tsq   = (const float*)d_in[2];  // [16]
  const float* dsq   = (const float*)d_in[3];  // [16]
  const int*   snd   = (const int*)d_in[4];    // [E]
  const int*   rcv   = (const int*)d_in[5];    // [E]
  float* out = (float*)d_out;

  int E = in_sizes[1];
  int N = in_sizes[0] / 48;  // rcv16 packing assumes N < 65536

  int NS = (N + (1 << SR_BITS) - 1) >> SR_BITS;  // node subranges (4)
  int NC = (E + (1 << CH_BITS) - 1) >> CH_BITS;  // edge chunks (49)

  // workspace (~23MB): row_start[N+4] | aux(btot) | pair 4B | partial2 |
  //   boffL-region | pos(E bytes)
  // f16 carve inside partial2+boffL (13.0MB, dead before their writers):
  // xtmp_h4 [0,6.4M) by flow1 (after fill), nodes_h4 [6.4,12.8M) by scanCD
  // (disjoint from partial2 [0,3.2M) and live boffL [3.2,5.65M)).
  size_t padN  = (size_t)E + 7 * (size_t)N + 64;  // >= pad8 total + slack
  size_t rsB   = al16((size_t)(N + 4) * 4);
  size_t auxB  = 512;
  size_t pairB = al16(padN * 4);
  size_t p2B   = al16((size_t)NS * NC << SR_BITS);  // uchar
  size_t xh4B  = al16((size_t)N * 16 * 8);          // one f16x4 buffer
  size_t boffB = al16((size_t)NC * N * 4);
  if (p2B + boffB < 2 * xh4B) boffB = 2 * xh4B - p2B;  // safety

  char* base = (char*)d_ws;
  int*           row_start = (int*)base;
  int*           btot      = (int*)(base + rsB);        // [64]
  int*           pair      = (int*)(base + rsB + auxB);
  unsigned char* partial2  = (unsigned char*)(base + rsB + auxB + pairB);
  unsigned char* boffL     = partial2 + p2B;
  unsigned char* pos       = boffL + boffB;
  vh4*           xtmp_h4   = (vh4*)partial2;          // dead region after fill
  vh4*           nodes_h4  = (vh4*)(partial2 + xh4B);

  int E4  = E >> 2;
  int nb  = (N + 1023) / 1024;   // tiles (<=64 required; 49 @ N=50K)
  int nb2 = (N + 255) / 256;
  int fbk = (E4 + 511) / 512;
  int nfb = (N + 3) / 4;

  hipMemsetAsync(pair, 0, pairB, stream);  // zero pad slots (w=0, rcv=0)
  lhist_kernel<<<dim3(NC, NS), 256, 0, stream>>>(snd, pos, partial2, E, NC);
  scan1A_kernel<<<nb, 1024, 0, stream>>>(partial2, boffL, row_start, btot, N, NC);
  scanCD_kernel<<<nb2, 256, 0, stream>>>(row_start, btot, nodes, nodes_h4, N, nb);
  fill_kernel<<<fbk, 256, 0, stream>>>((const vi4*)snd, (const vi4*)rcv,
                                       (const vf4*)ew, pos, boffL, row_start,
                                       pair, snd, rcv, ew, N, E);

  // step1: p=nodes(f32), q=nodes_h4 -> writes out(f32 scratch) + xtmp_h4
  // step2: p=out(f32),   q=xtmp_h4  -> overwrites out (final)
  flowp_kernel<<<nfb, 256, 0, stream>>>(nodes_h4, nodes, row_start, pair,
                                        tsq, dsq, out, xtmp_h4, N);
  flowp_kernel<<<nfb, 256, 0, stream>>>(xtmp_h4, out, row_start, pair,
                                        tsq, dsq, out, nullptr, N);
}

// Round 10
// 257.325 us; speedup vs baseline: 1.4611x; 1.0485x over previous
//
#include <hip/hip_runtime.h>
#include <math.h>

// FlowLayer: 2 steps of manifold (S^2) graph heat flow.
// N=50000 nodes, C=16, D=3, E=1.6M edges.
//
// R28 = R27 (best, 269.8us) with build LAUNCH-SHAPE fixes only:
//  - lhist: 1024 thr/block + SR_BITS 14->13 (32KB LDS, NS=7): grid
//    196->343 blocks, per-block serial edge-stream 32->8 vi4-iters.
//    R27 shape had 0.76 waves/SIMD and 60+ idle CUs.
//  - scan1A: 256-thread tiles -> 196 blocks (was 49 blocks = 49 CUs!).
//  - scanCD: 256-wide two-level btot scan (nb=196 > 64 now), still fused
//    with f32->f16x4 convert.
// flowp + fill + memset byte-identical to R27.
// Build is occupancy-bound, not traffic-bound (~90MB ~= 15-20us floor vs
// 157us measured) -- grids of 49-196 small blocks stranded most CUs.
//
// flowp floor ~56us: divergent-gather floor -- six falsified levers
// (bytes -65%->-7%, VALU -11%->-2%, TLP x2 worse, atomics disaster,
// SW pipeline compiler-collapsed, nontemporal worse). FROZEN.
// R18: no aggregate locals in flowp. R20: alignment beats bytes.
//
// NOTE: |u|^2 MUST be computed from u's components (not 1-cs^2): near
// antipodal pairs 1-cs^2 cancels catastrophically -> rsq explodes (R5 bug).

constexpr float EPS64F = 2.2204460492503131e-16f;  // np.float64 eps
constexpr float PI_F   = 3.14159265358979323846f;
constexpr int   SR_BITS = 13;                 // 8192-node subranges (32KB LDS)
constexpr int   CH_BITS = 15;                 // 32768-edge chunks

typedef int      vi4 __attribute__((ext_vector_type(4)));
typedef float    vf4 __attribute__((ext_vector_type(4)));
typedef float    vf2 __attribute__((ext_vector_type(2)));
typedef _Float16 vh4 __attribute__((ext_vector_type(4)));

// ---------------- CSR build ----------------

// LDS histogram: block (c = blockIdx.x, s = blockIdx.y), 1024 threads.
__global__ __launch_bounds__(1024) void lhist_kernel(
    const int* __restrict__ snd, unsigned char* __restrict__ pos,
    unsigned char* __restrict__ partial2, int E, int NC) {
  __shared__ int h[1 << SR_BITS];
  int tid = threadIdx.x;
  int c = blockIdx.x, s = blockIdx.y;
  for (int i = tid; i < (1 << SR_BITS); i += 1024) h[i] = 0;
  __syncthreads();
  int base = c << CH_BITS;
  int cnt = min(1 << CH_BITS, E - base);
  int s0 = s << SR_BITS;
  const vi4* snd4 = (const vi4*)(snd + base);  // base is 32768-aligned
  int cnt4 = cnt >> 2;
  for (int i = tid; i < cnt4; i += 1024) {
    vi4 sv = snd4[i];
    int e = base + (i << 2);
    int v;
    v = sv.x - s0; if ((unsigned)v < (1u << SR_BITS)) pos[e]     = (unsigned char)atomicAdd(&h[v], 1);
    v = sv.y - s0; if ((unsigned)v < (1u << SR_BITS)) pos[e + 1] = (unsigned char)atomicAdd(&h[v], 1);
    v = sv.z - s0; if ((unsigned)v < (1u << SR_BITS)) pos[e + 2] = (unsigned char)atomicAdd(&h[v], 1);
    v = sv.w - s0; if ((unsigned)v < (1u << SR_BITS)) pos[e + 3] = (unsigned char)atomicAdd(&h[v], 1);
  }
  if (tid == 0) {  // chunk tail (cnt % 4)
    for (int i = cnt4 << 2; i < cnt; ++i) {
      int v = snd[base + i] - s0;
      if ((unsigned)v < (1u << SR_BITS))
        pos[base + i] = (unsigned char)atomicAdd(&h[v], 1);
    }
  }
  __syncthreads();
  unsigned char* dst = partial2 + ((size_t)(s * NC + c) << SR_BITS);
  for (int i = tid; i < (1 << SR_BITS); i += 1024)
    dst[i] = (unsigned char)h[i];
}

// Fused scan1+scanA with row padding (PAD 8), 256-thread tiles: per-node
// exclusive fold over chunks (boffL uchar) -> degree; two-level shfl/LDS
// scan of padded degree -> tile-local exclusive row_start + tile totals.
__global__ __launch_bounds__(256) void scan1A_kernel(
    const unsigned char* __restrict__ partial2, unsigned char* __restrict__ boffL,
    int* __restrict__ row_start, int* __restrict__ btot, int N, int NC) {
  __shared__ int wsum[4];
  int tid = threadIdx.x;
  int lane = tid & 63, wave = tid >> 6;
  int i = blockIdx.x * 256 + tid;
  int vpad = 0;
  if (i < N) {
    int s = i >> SR_BITS, lv = i & ((1 << SR_BITS) - 1);
    int run = 0;
    for (int c = 0; c < NC; ++c) {
      int t = partial2[((size_t)(s * NC + c) << SR_BITS) + lv];
      boffL[(size_t)c * N + i] = (unsigned char)run;  // run <= degree <= ~80
      run += t;
    }
    vpad = (run + 7) & ~7;  // padded degree (PAD 8)
  }
  int incl = vpad;
  #pragma unroll
  for (int off = 1; off < 64; off <<= 1) {
    int t = __shfl_up(incl, off, 64);
    if (lane >= off) incl += t;
  }
  if (lane == 63) wsum[wave] = incl;
  __syncthreads();
  if (wave == 0 && lane < 4) {
    int wincl = wsum[lane];
    #pragma unroll
    for (int off = 1; off < 4; off <<= 1) {
      int t = __shfl_up(wincl, off, 64);
      if (lane >= off) wincl += t;
    }
    wsum[lane] = wincl;
  }
  __syncthreads();
  int woff = (wave > 0) ? wsum[wave - 1] : 0;
  if (i < N) row_start[i] = woff + incl - vpad;  // tile-local exclusive
  if (tid == 0) btot[blockIdx.x] = wsum[3];
}

// scanCD: 256-wide two-level scan of tile totals (nb <= 256) -> finalize
// row_start. Fused: nodes(f32) -> nodes_h4 (f16x4 8B [node*16+c]).
__global__ __launch_bounds__(256) void scanCD_kernel(
    int* __restrict__ row_start, const int* __restrict__ btot,
    const float* __restrict__ nodes, vh4* __restrict__ nodes_h4,
    int N, int nb) {
  __shared__ int bsh[256];
  __shared__ int wtot[4];
  int tid = threadIdx.x;
  int lane = tid & 63, wave = tid >> 6;
  int v = (tid < nb) ? btot[tid] : 0;
  int incl = v;
  #pragma unroll
  for (int off = 1; off < 64; off <<= 1) {
    int t = __shfl_up(incl, off, 64);
    if (lane >= off) incl += t;
  }
  if (lane == 63) wtot[wave] = incl;
  __syncthreads();
  if (wave == 0 && lane < 4) {
    int wincl = wtot[lane];
    #pragma unroll
    for (int off = 1; off < 4; off <<= 1) {
      int t = __shfl_up(wincl, off, 64);
      if (lane >= off) wincl += t;
    }
    wtot[lane] = wincl;
  }
  __syncthreads();
  int woff = (wave > 0) ? wtot[wave - 1] : 0;
  bsh[tid] = woff + incl - v;  // exclusive tile offset
  if (blockIdx.x == 0 && tid == 0) row_start[N] = wtot[3];  // padded total
  __syncthreads();
  int i = blockIdx.x * 256 + tid;
  if (i < N) row_start[i] = row_start[i] + bsh[blockIdx.x];  // tile==block
  // fused f32 -> f16x4 conversion: N*16 records (coalesced 12B reads / 8B
  // writes across consecutive threads).
  int total = N * 16;
  for (int idx = blockIdx.x * 256 + tid; idx < total; idx += gridDim.x * 256) {
    const float* s = nodes + idx * 3;
    vh4 h = {(_Float16)s[0], (_Float16)s[1], (_Float16)s[2], (_Float16)0.f};
    nodes_h4[idx] = h;
  }
}

// Atomic-free fill: slot = row_start[snd] + boffL[chunk][snd] + pos[e];
// packs 4B (w 16-bit fixed << 16 | rcv16). Pad slots stay zero from the
// memset (w=0, rcv=0). row_start + chunk's boffL slice are L2-resident.
__global__ __launch_bounds__(256) void fill_kernel(
    const vi4* __restrict__ snd4, const vi4* __restrict__ rcv4,
    const vf4* __restrict__ ew4, const unsigned char* __restrict__ pos,
    const unsigned char* __restrict__ boffL, const int* __restrict__ row_start,
    int* __restrict__ pair,
    const int* __restrict__ snd, const int* __restrict__ rcv,
    const float* __restrict__ ew, int N, int E) {
  int tid = threadIdx.x;
  int E4 = E >> 2;
  #pragma unroll
  for (int gg = 0; gg < 2; ++gg) {
    int g = blockIdx.x * 512 + gg * 256 + tid;
    if (g < E4) {
      int e = g << 2;
      const unsigned char* bc = boffL + (size_t)(e >> CH_BITS) * N;  // same chunk e..e+3
      vi4 s = __builtin_nontemporal_load(&snd4[g]);
      vi4 r = __builtin_nontemporal_load(&rcv4[g]);
      vf4 w = __builtin_nontemporal_load(&ew4[g]);
      unsigned pb = *(const unsigned*)(pos + e);
      int rs0 = row_start[s.x] + bc[s.x];
      int rs1 = row_start[s.y] + bc[s.y];
      int rs2 = row_start[s.z] + bc[s.z];
      int rs3 = row_start[s.w] + bc[s.w];
      unsigned e0 = ((unsigned)(int)fmaf(w.x, 65535.f, 0.5f) << 16) | (unsigned)r.x;
      unsigned e1 = ((unsigned)(int)fmaf(w.y, 65535.f, 0.5f) << 16) | (unsigned)r.y;
      unsigned e2 = ((unsigned)(int)fmaf(w.z, 65535.f, 0.5f) << 16) | (unsigned)r.z;
      unsigned e3 = ((unsigned)(int)fmaf(w.w, 65535.f, 0.5f) << 16) | (unsigned)r.w;
      pair[rs0 + (pb & 255u)]         = (int)e0;
      pair[rs1 + ((pb >> 8) & 255u)]  = (int)e1;
      pair[rs2 + ((pb >> 16) & 255u)] = (int)e2;
      pair[rs3 + (pb >> 24)]          = (int)e3;
    }
  }
  if (blockIdx.x == 0 && tid == 0) {
    for (int e = E4 << 2; e < E; ++e) {  // edge tail
      int sn = snd[e];
      pair[row_start[sn] + boffL[(size_t)(e >> CH_BITS) * N + sn] + pos[e]] =
          (int)(((unsigned)(int)fmaf(ew[e], 65535.f, 0.5f) << 16) | (unsigned)rcv[e]);
    }
  }
}

// ---------------- flow (R22/R27 structure, FROZEN) ----------------

__device__ __forceinline__ void edge_accum_pk(
    vf2 p0, vf2 p1, vf2 p2, vf2 q0, vf2 q1, vf2 q2, vf2 w,
    vf2& a0, vf2& a1, vf2& a2) {
  vf2 cs = p0 * q0 + p1 * q1 + p2 * q2;
  cs = __builtin_elementwise_min(vf2{1.f, 1.f},
       __builtin_elementwise_max(vf2{-1.f, -1.f}, cs));
  vf2 u0 = q0 - cs * p0;
  vf2 u1 = q1 - cs * p1;
  vf2 u2 = q2 - cs * p2;
  // |u|^2 from components (R5 lesson)
  vf2 un2 = __builtin_elementwise_max(u0 * u0 + u1 * u1 + u2 * u2,
                                      vf2{1e-24f, 1e-24f});
  // acos via A&S 4.4.45 (|err| <= 6.7e-5; output threshold is 2e-2)
  vf2 ax = __builtin_elementwise_abs(cs);
  vf2 s = __builtin_elementwise_sqrt(vf2{1.f, 1.f} - ax);
  vf2 poly = ((ax * -0.0187293f + 0.0742610f) * ax - 0.2121144f) * ax
             + 1.5707288f;
  vf2 th = s * poly;
  vf2 theta;
  theta.x = (cs.x >= 0.0f) ? th.x : (PI_F - th.x);
  theta.y = (cs.y >= 0.0f) ? th.y : (PI_F - th.y);
  vf2 rsq;
  rsq.x = __builtin_amdgcn_rsqf(un2.x);
  rsq.y = __builtin_amdgcn_rsqf(un2.y);
  vf2 coef = w * theta * rsq;
  a0 += coef * u0;
  a1 += coef * u1;
  a2 += coef * u2;
}

__device__ __forceinline__ void node_step(
    float a0, float a1, float a2, float ws, float p0, float p1, float p2,
    float ts, float dsv, float& y0, float& y1, float& y2) {
  // v_lap = -agg/deg; nrm/scale sign-invariant; -(v_lap*scale)*t = +g*scale*t
  float invdg = __builtin_amdgcn_rcpf(ws + 1e-12f);
  float g0 = a0 * invdg, g1 = a1 * invdg, g2 = a2 * invdg;
  float nrm = sqrtf(fmaf(g0, g0, fmaf(g1, g1, g2 * g2)) + EPS64F);
  float tch = ts * ts * 0.5f;  // t_sqrt^2 / N_STEPS
  float dch = dsv * dsv;
  float alp = __builtin_amdgcn_rcpf(1.0f + __expf(dch - nrm));  // sigmoid
  float scale = (nrm * alp <= 1.0f) ? alp : __builtin_amdgcn_rcpf(nrm);
  float f = scale * tch;
  float v0 = g0 * f, v1 = g1 * f, v2 = g2 * f;
  float nv = sqrtf(fmaf(v0, v0, fmaf(v1, v1, v2 * v2)));
  float cn = __cosf(nv);
  float sc = (nv > 1e-20f) ? (__sinf(nv) * __builtin_amdgcn_rcpf(nv)) : 1.0f;
  float t0 = fmaf(cn, p0, sc * v0);
  float t1 = fmaf(cn, p1, sc * v1);
  float t2 = fmaf(cn, p2, sc * v2);
  float inv = __builtin_amdgcn_rsqf(fmaf(t0, t0, fmaf(t1, t1, t2 * t2)));
  y0 = t0 * inv; y1 = t1 * inv; y2 = t2 * inv;
}

// Wave per node; lane = k*16+c; rows padded to 8 -> no guards: pads are
// (w=0, rcv=0) entries, always in-bounds. 8 edges/iter: lane k handles
// edges {j+k, j+4+k} as one vf2 pair.
// pair entry: 4B (w16fix<<16 | rcv16). q gather: ONE dwordx2 from f16x4
// records xh4[rcv*16+c]. p from f32 pf (nodes step1, d_out step2).
// Writes: of (f32, always) + oh4 (f16x4, step1 only). All math f32.
// Pair loads PLAIN (R26 lesson: nontemporal evicts L2 -> step2 refetch).
__global__ __launch_bounds__(256, 8) void flowp_kernel(
    const vh4* __restrict__ xh4, const float* __restrict__ pf,
    const int* __restrict__ row_start, const int* __restrict__ pair,
    const float* __restrict__ tsq, const float* __restrict__ dsq,
    float* __restrict__ of, vh4* __restrict__ oh4, int N) {
  int node = blockIdx.x * 4 + (threadIdx.x >> 6);
  if (node >= N) return;
  int lane = threadIdx.x & 63;
  int c = lane & 15;
  int k = lane >> 4;
  int c3 = c * 3;
  int beg = row_start[node];
  int end = row_start[node + 1];
  int ip = node * 48 + c3;
  float ps0 = pf[ip], ps1 = pf[ip + 1], ps2 = pf[ip + 2];
  vf2 p0 = {ps0, ps0}, p1 = {ps1, ps1}, p2 = {ps2, ps2};
  vf2 a0 = {0.f, 0.f}, a1 = {0.f, 0.f}, a2 = {0.f, 0.f}, wsv = {0.f, 0.f};
  const vh4* __restrict__ xc = xh4 + c;  // hoisted channel base
  int iters = (end - beg) >> 3;  // exact (rows padded to 8)
  int j = beg + k;
  constexpr float WS = 1.0f / 65535.0f;
  #pragma unroll 2
  for (int t = 0; t < iters; ++t, j += 8) {
    int e0 = pair[j];
    int e1 = pair[j + 4];
    float w0 = (float)((unsigned)e0 >> 16) * WS;
    float w1 = (float)((unsigned)e1 >> 16) * WS;
    vh4 qva = xc[(e0 & 0xFFFF) << 4];
    vh4 qvb = xc[(e1 & 0xFFFF) << 4];
    float qa0 = (float)qva.x, qa1 = (float)qva.y, qa2 = (float)qva.z;
    float qb0 = (float)qvb.x, qb1 = (float)qvb.y, qb2 = (float)qvb.z;
    vf2 wA = {w0, w1};
    edge_accum_pk(p0, p1, p2, vf2{qa0, qb0}, vf2{qa1, qb1},
                  vf2{qa2, qb2}, wA, a0, a1, a2);
    wsv += wA;
  }
  float A0 = a0.x + a0.y, A1 = a1.x + a1.y, A2 = a2.x + a2.y;
  float ws = wsv.x + wsv.y;
  A0 += __shfl_xor(A0, 16); A1 += __shfl_xor(A1, 16);
  A2 += __shfl_xor(A2, 16); ws += __shfl_xor(ws, 16);
  A0 += __shfl_xor(A0, 32); A1 += __shfl_xor(A1, 32);
  A2 += __shfl_xor(A2, 32); ws += __shfl_xor(ws, 32);
  if (k == 0) {
    float y0, y1, y2;
    node_step(A0, A1, A2, ws, ps0, ps1, ps2, tsq[c], dsq[c], y0, y1, y2);
    of[ip] = y0; of[ip + 1] = y1; of[ip + 2] = y2;
    if (oh4) {
      vh4 h = {(_Float16)y0, (_Float16)y1, (_Float16)y2, (_Float16)0.f};
      oh4[node * 16 + c] = h;
    }
  }
}

static inline size_t al16(size_t x) { return (x + 15) & ~(size_t)15; }

extern "C" void kernel_launch(void* const* d_in, const int* in_sizes, int n_in,
                              void* d_out, int out_size, void* d_ws, size_t ws_size,
                              hipStream_t stream) {
  const float* nodes = (const float*)d_in[0];  // [N,16,3]
  const float* ew    = (const float*)d_in[1];  // [E]
  const float* tsq   = (const float*)d_in[2];  // [16]
  const float* dsq   = (const float*)d_in[3];  // [16]
  const int*   snd   = (const int*)d_in[4];    // [E]
  const int*   rcv   = (const int*)d_in[5];    // [E]
  float* out = (float*)d_out;

  int E = in_sizes[1];
  int N = in_sizes[0] / 48;  // rcv16 packing assumes N < 65536

  int NS = (N + (1 << SR_BITS) - 1) >> SR_BITS;  // node subranges (7)
  int NC = (E + (1 << CH_BITS) - 1) >> CH_BITS;  // edge chunks (49)

  // workspace (~22MB): row_start[N+4] | aux(btot[256]) | pair 4B |
  //   partial2(2.7M) | boffL-region | pos(E bytes)
  // f16 carve inside partial2+boffL (>=12.8MB via safety): xtmp_h4
  // [0,6.4M) by flow1 (after fill; partial2/boffL dead), nodes_h4
  // [6.4,12.8M) by scanCD (disjoint from partial2 [0,2.7M) and live
  // boffL [2.7,5.15M)).
  size_t padN  = (size_t)E + 7 * (size_t)N + 64;  // >= pad8 total + slack
  size_t rsB   = al16((size_t)(N + 4) * 4);
  size_t auxB  = 1536;                             // btot[<=256] + pad
  size_t pairB = al16(padN * 4);
  size_t p2B   = al16((size_t)NS * NC << SR_BITS);  // uchar
  size_t xh4B  = al16((size_t)N * 16 * 8);          // one f16x4 buffer
  size_t boffB = al16((size_t)NC * N * 4);
  if (p2B + boffB < 2 * xh4B) boffB = 2 * xh4B - p2B;  // carve safety

  char* base = (char*)d_ws;
  int*           row_start = (int*)base;
  int*           btot      = (int*)(base + rsB);        // [<=256]
  int*           pair      = (int*)(base + rsB + auxB);
  unsigned char* partial2  = (unsigned char*)(base + rsB + auxB + pairB);
  unsigned char* boffL     = partial2 + p2B;
  unsigned char* pos       = boffL + boffB;
  vh4*           xtmp_h4   = (vh4*)partial2;          // dead region after fill
  vh4*           nodes_h4  = (vh4*)(partial2 + xh4B);

  int E4  = E >> 2;
  int nb  = (N + 255) / 256;     // scan tiles (<=256 required; 196 @ N=50K)
  int fbk = (E4 + 511) / 512;
  int nfb = (N + 3) / 4;

  hipMemsetAsync(pair, 0, pairB, stream);  // zero pad slots (w=0, rcv=0)
  lhist_kernel<<<dim3(NC, NS), 1024, 0, stream>>>(snd, pos, partial2, E, NC);
  scan1A_kernel<<<nb, 256, 0, stream>>>(partial2, boffL, row_start, btot, N, NC);
  scanCD_kernel<<<nb, 256, 0, stream>>>(row_start, btot, nodes, nodes_h4, N, nb);
  fill_kernel<<<fbk, 256, 0, stream>>>((const vi4*)snd, (const vi4*)rcv,
                                       (const vf4*)ew, pos, boffL, row_start,
                                       pair, snd, rcv, ew, N, E);

  // step1: p=nodes(f32), q=nodes_h4 -> writes out(f32 scratch) + xtmp_h4
  // step2: p=out(f32),   q=xtmp_h4  -> overwrites out (final)
  flowp_kernel<<<nfb, 256, 0, stream>>>(nodes_h4, nodes, row_start, pair,
                                        tsq, dsq, out, xtmp_h4, N);
  flowp_kernel<<<nfb, 256, 0, stream>>>(xtmp_h4, out, row_start, pair,
                                        tsq, dsq, out, nullptr, N);
}

// Round 11
// 252.194 us; speedup vs baseline: 1.4909x; 1.0203x over previous
//
#include <hip/hip_runtime.h>
#include <math.h>

// FlowLayer: 2 steps of manifold (S^2) graph heat flow.
// N=50000 nodes, C=16, D=3, E=1.6M edges.
//
// R29 = R28 (257.3us) with ONE change: SINGLE-PASS lhist.
// Old lhist re-read snd NS=7 times (44.8MB, 6/7 of loads guard-discarded)
// because 32-bit LDS counters for N=50K need 200KB. Fix: PACKED-BYTE LDS
// histogram -- per-(chunk,node) count <= degree <= ~80 < 255, so byte
// counters packed 4/int: atomicAdd(&h32[v>>2], 1<<((v&3)*8)); returned
// word's byte at our shift = exact pre-increment rank (no cross-byte
// carry possible; sibling-byte concurrency can't disturb our byte's old
// value). LDS = 50KB/block (gfx950 max workgroup LDS 160KB).
// -> one block per 32K-edge chunk (49 blocks x 1024 thr), snd read ONCE,
// partial2 becomes [chunk][node] uchar (2.45MB). scan1A re-indexed.
// Everything else byte-identical to R28.
//
// flowp floor ~56us: divergent-gather floor -- six falsified levers
// (bytes -65%->-7%, VALU -11%->-2%, TLP x2 worse, atomics disaster,
// SW pipeline compiler-collapsed, nontemporal worse). FROZEN.
// R18: no aggregate locals in flowp. R20: alignment beats bytes.
// R25: global atomicAdd-with-return = disaster (LDS atomics are fine).
//
// NOTE: |u|^2 MUST be computed from u's components (not 1-cs^2): near
// antipodal pairs 1-cs^2 cancels catastrophically -> rsq explodes (R5 bug).

constexpr float EPS64F = 2.2204460492503131e-16f;  // np.float64 eps
constexpr float PI_F   = 3.14159265358979323846f;
constexpr int   CH_BITS = 15;                 // 32768-edge chunks

typedef int      vi4 __attribute__((ext_vector_type(4)));
typedef float    vf4 __attribute__((ext_vector_type(4)));
typedef float    vf2 __attribute__((ext_vector_type(2)));
typedef _Float16 vh4 __attribute__((ext_vector_type(4)));

// ---------------- CSR build ----------------

// Single-pass LDS byte-histogram: one block per chunk. h = uchar[N]
// packed 4-per-int in dynamic LDS. pos[e] = pre-increment byte rank.
__global__ __launch_bounds__(1024) void lhist_kernel(
    const int* __restrict__ snd, unsigned char* __restrict__ pos,
    unsigned char* __restrict__ partial2, int E, int N) {
  extern __shared__ int h32[];   // ceil(N/4) ints = N byte counters
  int tid = threadIdx.x;
  int c = blockIdx.x;
  int nW = (N + 3) >> 2;
  for (int i = tid; i < nW; i += 1024) h32[i] = 0;
  __syncthreads();
  int base = c << CH_BITS;
  int cnt = min(1 << CH_BITS, E - base);
  const vi4* snd4 = (const vi4*)(snd + base);  // base is 32768-aligned
  int cnt4 = cnt >> 2;
  for (int i = tid; i < cnt4; i += 1024) {
    vi4 sv = snd4[i];
    int e = base + (i << 2);
    int v, sh, old;
    v = sv.x; sh = (v & 3) << 3;
    old = atomicAdd(&h32[v >> 2], 1 << sh);
    pos[e]     = (unsigned char)((old >> sh) & 255);
    v = sv.y; sh = (v & 3) << 3;
    old = atomicAdd(&h32[v >> 2], 1 << sh);
    pos[e + 1] = (unsigned char)((old >> sh) & 255);
    v = sv.z; sh = (v & 3) << 3;
    old = atomicAdd(&h32[v >> 2], 1 << sh);
    pos[e + 2] = (unsigned char)((old >> sh) & 255);
    v = sv.w; sh = (v & 3) << 3;
    old = atomicAdd(&h32[v >> 2], 1 << sh);
    pos[e + 3] = (unsigned char)((old >> sh) & 255);
  }
  if (tid == 0) {  // chunk tail (cnt % 4)
    for (int i = cnt4 << 2; i < cnt; ++i) {
      int v = snd[base + i];
      int sh = (v & 3) << 3;
      int old = atomicAdd(&h32[v >> 2], 1 << sh);
      pos[base + i] = (unsigned char)((old >> sh) & 255);
    }
  }
  __syncthreads();
  // write per-chunk per-node counts: partial2[c*N + i] (uchar)
  unsigned char* dst = partial2 + (size_t)c * N;
  const unsigned char* hb = (const unsigned char*)h32;
  for (int i = tid; i < N; i += 1024) dst[i] = hb[i];
}

// Fused scan1+scanA with row padding (PAD 8), 256-thread tiles: per-node
// exclusive fold over chunks (boffL uchar) -> degree; two-level shfl/LDS
// scan of padded degree -> tile-local exclusive row_start + tile totals.
__global__ __launch_bounds__(256) void scan1A_kernel(
    const unsigned char* __restrict__ partial2, unsigned char* __restrict__ boffL,
    int* __restrict__ row_start, int* __restrict__ btot, int N, int NC) {
  __shared__ int wsum[4];
  int tid = threadIdx.x;
  int lane = tid & 63, wave = tid >> 6;
  int i = blockIdx.x * 256 + tid;
  int vpad = 0;
  if (i < N) {
    int run = 0;
    for (int c = 0; c < NC; ++c) {
      int t = partial2[(size_t)c * N + i];
      boffL[(size_t)c * N + i] = (unsigned char)run;  // run <= degree <= ~80
      run += t;
    }
    vpad = (run + 7) & ~7;  // padded degree (PAD 8)
  }
  int incl = vpad;
  #pragma unroll
  for (int off = 1; off < 64; off <<= 1) {
    int t = __shfl_up(incl, off, 64);
    if (lane >= off) incl += t;
  }
  if (lane == 63) wsum[wave] = incl;
  __syncthreads();
  if (wave == 0 && lane < 4) {
    int wincl = wsum[lane];
    #pragma unroll
    for (int off = 1; off < 4; off <<= 1) {
      int t = __shfl_up(wincl, off, 64);
      if (lane >= off) wincl += t;
    }
    wsum[lane] = wincl;
  }
  __syncthreads();
  int woff = (wave > 0) ? wsum[wave - 1] : 0;
  if (i < N) row_start[i] = woff + incl - vpad;  // tile-local exclusive
  if (tid == 0) btot[blockIdx.x] = wsum[3];
}

// scanCD: 256-wide two-level scan of tile totals (nb <= 256) -> finalize
// row_start. Fused: nodes(f32) -> nodes_h4 (f16x4 8B [node*16+c]).
__global__ __launch_bounds__(256) void scanCD_kernel(
    int* __restrict__ row_start, const int* __restrict__ btot,
    const float* __restrict__ nodes, vh4* __restrict__ nodes_h4,
    int N, int nb) {
  __shared__ int bsh[256];
  __shared__ int wtot[4];
  int tid = threadIdx.x;
  int lane = tid & 63, wave = tid >> 6;
  int v = (tid < nb) ? btot[tid] : 0;
  int incl = v;
  #pragma unroll
  for (int off = 1; off < 64; off <<= 1) {
    int t = __shfl_up(incl, off, 64);
    if (lane >= off) incl += t;
  }
  if (lane == 63) wtot[wave] = incl;
  __syncthreads();
  if (wave == 0 && lane < 4) {
    int wincl = wtot[lane];
    #pragma unroll
    for (int off = 1; off < 4; off <<= 1) {
      int t = __shfl_up(wincl, off, 64);
      if (lane >= off) wincl += t;
    }
    wtot[lane] = wincl;
  }
  __syncthreads();
  int woff = (wave > 0) ? wtot[wave - 1] : 0;
  bsh[tid] = woff + incl - v;  // exclusive tile offset
  if (blockIdx.x == 0 && tid == 0) row_start[N] = wtot[3];  // padded total
  __syncthreads();
  int i = blockIdx.x * 256 + tid;
  if (i < N) row_start[i] = row_start[i] + bsh[blockIdx.x];  // tile==block
  // fused f32 -> f16x4 conversion: N*16 records (coalesced 12B reads / 8B
  // writes across consecutive threads).
  int total = N * 16;
  for (int idx = blockIdx.x * 256 + tid; idx < total; idx += gridDim.x * 256) {
    const float* s = nodes + idx * 3;
    vh4 h = {(_Float16)s[0], (_Float16)s[1], (_Float16)s[2], (_Float16)0.f};
    nodes_h4[idx] = h;
  }
}

// Atomic-free fill: slot = row_start[snd] + boffL[chunk][snd] + pos[e];
// packs 4B (w 16-bit fixed << 16 | rcv16). Pad slots stay zero from the
// memset (w=0, rcv=0). row_start + chunk's boffL slice are L2-resident.
__global__ __launch_bounds__(256) void fill_kernel(
    const vi4* __restrict__ snd4, const vi4* __restrict__ rcv4,
    const vf4* __restrict__ ew4, const unsigned char* __restrict__ pos,
    const unsigned char* __restrict__ boffL, const int* __restrict__ row_start,
    int* __restrict__ pair,
    const int* __restrict__ snd, const int* __restrict__ rcv,
    const float* __restrict__ ew, int N, int E) {
  int tid = threadIdx.x;
  int E4 = E >> 2;
  #pragma unroll
  for (int gg = 0; gg < 2; ++gg) {
    int g = blockIdx.x * 512 + gg * 256 + tid;
    if (g < E4) {
      int e = g << 2;
      const unsigned char* bc = boffL + (size_t)(e >> CH_BITS) * N;  // same chunk e..e+3
      vi4 s = __builtin_nontemporal_load(&snd4[g]);
      vi4 r = __builtin_nontemporal_load(&rcv4[g]);
      vf4 w = __builtin_nontemporal_load(&ew4[g]);
      unsigned pb = *(const unsigned*)(pos + e);
      int rs0 = row_start[s.x] + bc[s.x];
      int rs1 = row_start[s.y] + bc[s.y];
      int rs2 = row_start[s.z] + bc[s.z];
      int rs3 = row_start[s.w] + bc[s.w];
      unsigned e0 = ((unsigned)(int)fmaf(w.x, 65535.f, 0.5f) << 16) | (unsigned)r.x;
      unsigned e1 = ((unsigned)(int)fmaf(w.y, 65535.f, 0.5f) << 16) | (unsigned)r.y;
      unsigned e2 = ((unsigned)(int)fmaf(w.z, 65535.f, 0.5f) << 16) | (unsigned)r.z;
      unsigned e3 = ((unsigned)(int)fmaf(w.w, 65535.f, 0.5f) << 16) | (unsigned)r.w;
      pair[rs0 + (pb & 255u)]         = (int)e0;
      pair[rs1 + ((pb >> 8) & 255u)]  = (int)e1;
      pair[rs2 + ((pb >> 16) & 255u)] = (int)e2;
      pair[rs3 + (pb >> 24)]          = (int)e3;
    }
  }
  if (blockIdx.x == 0 && tid == 0) {
    for (int e = E4 << 2; e < E; ++e) {  // edge tail
      int sn = snd[e];
      pair[row_start[sn] + boffL[(size_t)(e >> CH_BITS) * N + sn] + pos[e]] =
          (int)(((unsigned)(int)fmaf(ew[e], 65535.f, 0.5f) << 16) | (unsigned)rcv[e]);
    }
  }
}

// ---------------- flow (R22/R27 structure, FROZEN) ----------------

__device__ __forceinline__ void edge_accum_pk(
    vf2 p0, vf2 p1, vf2 p2, vf2 q0, vf2 q1, vf2 q2, vf2 w,
    vf2& a0, vf2& a1, vf2& a2) {
  vf2 cs = p0 * q0 + p1 * q1 + p2 * q2;
  cs = __builtin_elementwise_min(vf2{1.f, 1.f},
       __builtin_elementwise_max(vf2{-1.f, -1.f}, cs));
  vf2 u0 = q0 - cs * p0;
  vf2 u1 = q1 - cs * p1;
  vf2 u2 = q2 - cs * p2;
  // |u|^2 from components (R5 lesson)
  vf2 un2 = __builtin_elementwise_max(u0 * u0 + u1 * u1 + u2 * u2,
                                      vf2{1e-24f, 1e-24f});
  // acos via A&S 4.4.45 (|err| <= 6.7e-5; output threshold is 2e-2)
  vf2 ax = __builtin_elementwise_abs(cs);
  vf2 s = __builtin_elementwise_sqrt(vf2{1.f, 1.f} - ax);
  vf2 poly = ((ax * -0.0187293f + 0.0742610f) * ax - 0.2121144f) * ax
             + 1.5707288f;
  vf2 th = s * poly;
  vf2 theta;
  theta.x = (cs.x >= 0.0f) ? th.x : (PI_F - th.x);
  theta.y = (cs.y >= 0.0f) ? th.y : (PI_F - th.y);
  vf2 rsq;
  rsq.x = __builtin_amdgcn_rsqf(un2.x);
  rsq.y = __builtin_amdgcn_rsqf(un2.y);
  vf2 coef = w * theta * rsq;
  a0 += coef * u0;
  a1 += coef * u1;
  a2 += coef * u2;
}

__device__ __forceinline__ void node_step(
    float a0, float a1, float a2, float ws, float p0, float p1, float p2,
    float ts, float dsv, float& y0, float& y1, float& y2) {
  // v_lap = -agg/deg; nrm/scale sign-invariant; -(v_lap*scale)*t = +g*scale*t
  float invdg = __builtin_amdgcn_rcpf(ws + 1e-12f);
  float g0 = a0 * invdg, g1 = a1 * invdg, g2 = a2 * invdg;
  float nrm = sqrtf(fmaf(g0, g0, fmaf(g1, g1, g2 * g2)) + EPS64F);
  float tch = ts * ts * 0.5f;  // t_sqrt^2 / N_STEPS
  float dch = dsv * dsv;
  float alp = __builtin_amdgcn_rcpf(1.0f + __expf(dch - nrm));  // sigmoid
  float scale = (nrm * alp <= 1.0f) ? alp : __builtin_amdgcn_rcpf(nrm);
  float f = scale * tch;
  float v0 = g0 * f, v1 = g1 * f, v2 = g2 * f;
  float nv = sqrtf(fmaf(v0, v0, fmaf(v1, v1, v2 * v2)));
  float cn = __cosf(nv);
  float sc = (nv > 1e-20f) ? (__sinf(nv) * __builtin_amdgcn_rcpf(nv)) : 1.0f;
  float t0 = fmaf(cn, p0, sc * v0);
  float t1 = fmaf(cn, p1, sc * v1);
  float t2 = fmaf(cn, p2, sc * v2);
  float inv = __builtin_amdgcn_rsqf(fmaf(t0, t0, fmaf(t1, t1, t2 * t2)));
  y0 = t0 * inv; y1 = t1 * inv; y2 = t2 * inv;
}

// Wave per node; lane = k*16+c; rows padded to 8 -> no guards: pads are
// (w=0, rcv=0) entries, always in-bounds. 8 edges/iter: lane k handles
// edges {j+k, j+4+k} as one vf2 pair.
// pair entry: 4B (w16fix<<16 | rcv16). q gather: ONE dwordx2 from f16x4
// records xh4[rcv*16+c]. p from f32 pf (nodes step1, d_out step2).
// Writes: of (f32, always) + oh4 (f16x4, step1 only). All math f32.
// Pair loads PLAIN (R26 lesson: nontemporal evicts L2 -> step2 refetch).
__global__ __launch_bounds__(256, 8) void flowp_kernel(
    const vh4* __restrict__ xh4, const float* __restrict__ pf,
    const int* __restrict__ row_start, const int* __restrict__ pair,
    const float* __restrict__ tsq, const float* __restrict__ dsq,
    float* __restrict__ of, vh4* __restrict__ oh4, int N) {
  int node = blockIdx.x * 4 + (threadIdx.x >> 6);
  if (node >= N) return;
  int lane = threadIdx.x & 63;
  int c = lane & 15;
  int k = lane >> 4;
  int c3 = c * 3;
  int beg = row_start[node];
  int end = row_start[node + 1];
  int ip = node * 48 + c3;
  float ps0 = pf[ip], ps1 = pf[ip + 1], ps2 = pf[ip + 2];
  vf2 p0 = {ps0, ps0}, p1 = {ps1, ps1}, p2 = {ps2, ps2};
  vf2 a0 = {0.f, 0.f}, a1 = {0.f, 0.f}, a2 = {0.f, 0.f}, wsv = {0.f, 0.f};
  const vh4* __restrict__ xc = xh4 + c;  // hoisted channel base
  int iters = (end - beg) >> 3;  // exact (rows padded to 8)
  int j = beg + k;
  constexpr float WS = 1.0f / 65535.0f;
  #pragma unroll 2
  for (int t = 0; t < iters; ++t, j += 8) {
    int e0 = pair[j];
    int e1 = pair[j + 4];
    float w0 = (float)((unsigned)e0 >> 16) * WS;
    float w1 = (float)((unsigned)e1 >> 16) * WS;
    vh4 qva = xc[(e0 & 0xFFFF) << 4];
    vh4 qvb = xc[(e1 & 0xFFFF) << 4];
    float qa0 = (float)qva.x, qa1 = (float)qva.y, qa2 = (float)qva.z;
    float qb0 = (float)qvb.x, qb1 = (float)qvb.y, qb2 = (float)qvb.z;
    vf2 wA = {w0, w1};
    edge_accum_pk(p0, p1, p2, vf2{qa0, qb0}, vf2{qa1, qb1},
                  vf2{qa2, qb2}, wA, a0, a1, a2);
    wsv += wA;
  }
  float A0 = a0.x + a0.y, A1 = a1.x + a1.y, A2 = a2.x + a2.y;
  float ws = wsv.x + wsv.y;
  A0 += __shfl_xor(A0, 16); A1 += __shfl_xor(A1, 16);
  A2 += __shfl_xor(A2, 16); ws += __shfl_xor(ws, 16);
  A0 += __shfl_xor(A0, 32); A1 += __shfl_xor(A1, 32);
  A2 += __shfl_xor(A2, 32); ws += __shfl_xor(ws, 32);
  if (k == 0) {
    float y0, y1, y2;
    node_step(A0, A1, A2, ws, ps0, ps1, ps2, tsq[c], dsq[c], y0, y1, y2);
    of[ip] = y0; of[ip + 1] = y1; of[ip + 2] = y2;
    if (oh4) {
      vh4 h = {(_Float16)y0, (_Float16)y1, (_Float16)y2, (_Float16)0.f};
      oh4[node * 16 + c] = h;
    }
  }
}

static inline size_t al16(size_t x) { return (x + 15) & ~(size_t)15; }

extern "C" void kernel_launch(void* const* d_in, const int* in_sizes, int n_in,
                              void* d_out, int out_size, void* d_ws, size_t ws_size,
                              hipStream_t stream) {
  const float* nodes = (const float*)d_in[0];  // [N,16,3]
  const float* ew    = (const float*)d_in[1];  // [E]
  const float* tsq   = (const float*)d_in[2];  // [16]
  const float* dsq   = (const float*)d_in[3];  // [16]
  const int*   snd   = (const int*)d_in[4];    // [E]
  const int*   rcv   = (const int*)d_in[5];    // [E]
  float* out = (float*)d_out;

  int E = in_sizes[1];
  int N = in_sizes[0] / 48;  // rcv16 packing assumes N < 65536

  int NC = (E + (1 << CH_BITS) - 1) >> CH_BITS;  // edge chunks (49)

  // workspace (~24MB): row_start[N+4] | aux(btot[256]) | pair 4B |
  //   partial2 (NC*N uchar, 2.45M) | boffL-region | pos(E bytes)
  // f16 carve inside partial2+boffL (>=12.8MB via safety): xtmp_h4
  // [0,6.4M) by flow1 (after fill; partial2/boffL dead), nodes_h4
  // [6.4,12.8M) by scanCD (disjoint from partial2 [0,2.45M) and live
  // boffL [2.45,4.9M)).
  size_t padN  = (size_t)E + 7 * (size_t)N + 64;  // >= pad8 total + slack
  size_t rsB   = al16((size_t)(N + 4) * 4);
  size_t auxB  = 1536;                             // btot[<=256] + pad
  size_t pairB = al16(padN * 4);
  size_t p2B   = al16((size_t)NC * N);              // uchar [chunk][node]
  size_t xh4B  = al16((size_t)N * 16 * 8);          // one f16x4 buffer
  size_t boffB = al16((size_t)NC * N * 4);
  if (p2B + boffB < 2 * xh4B) boffB = 2 * xh4B - p2B;  // carve safety

  char* base = (char*)d_ws;
  int*           row_start = (int*)base;
  int*           btot      = (int*)(base + rsB);        // [<=256]
  int*           pair      = (int*)(base + rsB + auxB);
  unsigned char* partial2  = (unsigned char*)(base + rsB + auxB + pairB);
  unsigned char* boffL     = partial2 + p2B;
  unsigned char* pos       = boffL + boffB;
  vh4*           xtmp_h4   = (vh4*)partial2;          // dead region after fill
  vh4*           nodes_h4  = (vh4*)(partial2 + xh4B);

  int E4  = E >> 2;
  int nb  = (N + 255) / 256;     // scan tiles (<=256 required; 196 @ N=50K)
  int fbk = (E4 + 511) / 512;
  int nfb = (N + 3) / 4;
  size_t ldsB = (size_t)(((N + 3) >> 2)) * 4;  // packed byte counters

  hipMemsetAsync(pair, 0, pairB, stream);  // zero pad slots (w=0, rcv=0)
  lhist_kernel<<<NC, 1024, ldsB, stream>>>(snd, pos, partial2, E, N);
  scan1A_kernel<<<nb, 256, 0, stream>>>(partial2, boffL, row_start, btot, N, NC);
  scanCD_kernel<<<nb, 256, 0, stream>>>(row_start, btot, nodes, nodes_h4, N, nb);
  fill_kernel<<<fbk, 256, 0, stream>>>((const vi4*)snd, (const vi4*)rcv,
                                       (const vf4*)ew, pos, boffL, row_start,
                                       pair, snd, rcv, ew, N, E);

  // step1: p=nodes(f32), q=nodes_h4 -> writes out(f32 scratch) + xtmp_h4
  // step2: p=out(f32),   q=xtmp_h4  -> overwrites out (final)
  flowp_kernel<<<nfb, 256, 0, stream>>>(nodes_h4, nodes, row_start, pair,
                                        tsq, dsq, out, xtmp_h4, N);
  flowp_kernel<<<nfb, 256, 0, stream>>>(xtmp_h4, out, row_start, pair,
                                        tsq, dsq, out, nullptr, N);
}